// Round 1
// baseline (2835.643 us; speedup 1.0000x reference)
//
#include <hip/hip_runtime.h>

#define NN 100000
#define NE 1600000
#define NG 512
#define DH 128
#define DH2 256

static inline size_t align256(size_t x) { return (x + 255) & ~size_t(255); }

// ---- graph structure ----------------------------------------------------
__global__ void count_k(const int* __restrict__ ei, const int* __restrict__ batch,
                        int* __restrict__ deg, int* __restrict__ gcnt) {
    int i = blockIdx.x * blockDim.x + threadIdx.x;
    if (i < NE) atomicAdd(&deg[ei[NE + i]], 1);   // dst row
    if (i < NN) atomicAdd(&gcnt[batch[i]], 1);
}

__global__ void scan_k(const int* __restrict__ deg, int* __restrict__ rowptr,
                       int* __restrict__ fillpos) {
    __shared__ int s[1024];
    int t = threadIdx.x;
    const int CH = (NN + 1023) / 1024;  // 98
    int beg = t * CH;
    int end = beg + CH; if (end > NN) end = NN;
    int sum = 0;
    for (int i = beg; i < end && i < NN; i++) sum += deg[i];
    s[t] = sum;
    __syncthreads();
    if (t == 0) {
        int run = 0;
        for (int i = 0; i < 1024; i++) { int v = s[i]; s[i] = run; run += v; }
    }
    __syncthreads();
    int run = s[t];
    for (int i = beg; i < end && i < NN; i++) {
        rowptr[i] = run; fillpos[i] = run; run += deg[i];
    }
    if (t == 1023) rowptr[NN] = run;  // t=1023 chunk is empty -> run == total
}

__global__ void fill_k(const int* __restrict__ ei, int* __restrict__ fillpos,
                       int* __restrict__ esrc) {
    int e = blockIdx.x * blockDim.x + threadIdx.x;
    if (e < NE) {
        int p = atomicAdd(&fillpos[ei[NE + e]], 1);
        esrc[p] = ei[e];  // src row
    }
}

__global__ void vinit_k(const float* __restrict__ emb, float* __restrict__ vfeat) {
    int i = blockIdx.x * blockDim.x + threadIdx.x;  // NG*DH
    vfeat[i] = emb[i & (DH - 1)];
}

// ---- aggregation: out[n] = in[n] + sum_{j in CSR(n)} in[src_j] ----------
__global__ __launch_bounds__(DH) void agg_k(const float* __restrict__ xin,
                                            const int* __restrict__ rowptr,
                                            const int* __restrict__ esrc,
                                            float* __restrict__ out) {
    int node = blockIdx.x;
    int c = threadIdx.x;
    float acc = xin[(size_t)node * DH + c];
    int beg = rowptr[node], end = rowptr[node + 1];
    int j = beg;
    for (; j + 3 < end; j += 4) {
        int s0 = esrc[j], s1 = esrc[j + 1], s2 = esrc[j + 2], s3 = esrc[j + 3];
        acc += xin[(size_t)s0 * DH + c] + xin[(size_t)s1 * DH + c]
             + xin[(size_t)s2 * DH + c] + xin[(size_t)s3 * DH + c];
    }
    for (; j < end; j++) acc += xin[(size_t)esrc[j] * DH + c];
    out[(size_t)node * DH + c] = acc;
}

__global__ __launch_bounds__(DH) void addvn_k(float* __restrict__ x,
                                              const float* __restrict__ vfeat,
                                              const int* __restrict__ batch) {
    int n = blockIdx.x; int c = threadIdx.x;
    x[(size_t)n * DH + c] += vfeat[(size_t)batch[n] * DH + c];
}

// ---- GEMM: C[M x NC] = A[M x K] @ W[K x NC] + bias, + column sum/sumsq --
// block = NC threads, 64-row tile staged in LDS (broadcast ds_read_b128).
template <int K, int NC>
__global__ __launch_bounds__(NC) void gemm_stats_k(
        const float* __restrict__ A, const float* __restrict__ W,
        const float* __restrict__ bias, float* __restrict__ C,
        float* __restrict__ csum, float* __restrict__ csq, int M) {
    __shared__ float4 atile[2048];  // 64 rows x 128 k = 32 KB
    const int tid = threadIdx.x;
    const int row0 = blockIdx.x * 64;
    float acc[64];
#pragma unroll
    for (int r = 0; r < 64; ++r) acc[r] = 0.f;

    for (int kc = 0; kc < K; kc += 128) {
        if (kc) __syncthreads();
        for (int i = tid; i < 2048; i += NC) {
            int row = i >> 5, kv = i & 31;
            int sr = row0 + row; if (sr >= M) sr = M - 1;
            atile[i] = *reinterpret_cast<const float4*>(A + (size_t)sr * K + kc + (kv << 2));
        }
        __syncthreads();
        const float* Wp = W + (size_t)kc * NC + tid;
        for (int kk = 0; kk < 128; kk += 4) {
            float w0 = Wp[(size_t)(kk + 0) * NC];
            float w1 = Wp[(size_t)(kk + 1) * NC];
            float w2 = Wp[(size_t)(kk + 2) * NC];
            float w3 = Wp[(size_t)(kk + 3) * NC];
            const float4* ap = atile + (kk >> 2);
#pragma unroll
            for (int r = 0; r < 64; ++r) {
                float4 a = ap[r * 32];
                acc[r] = fmaf(a.w, w3, fmaf(a.z, w2, fmaf(a.y, w1, fmaf(a.x, w0, acc[r]))));
            }
        }
    }
    float bv = bias[tid];
    float ls = 0.f, lsq = 0.f;
#pragma unroll
    for (int r = 0; r < 64; ++r) {
        int row = row0 + r;
        if (row < M) {
            float v = acc[r] + bv;
            C[(size_t)row * NC + tid] = v;
            ls += v; lsq += v * v;
        }
    }
    atomicAdd(&csum[tid], ls);
    atomicAdd(&csq[tid], lsq);
}

// ---- BN apply (+optional relu), stats finalized inline ------------------
__global__ void bnrelu_k(const float* __restrict__ in, float* __restrict__ out,
                         const float* __restrict__ csum, const float* __restrict__ csq,
                         const float* __restrict__ g, const float* __restrict__ b,
                         int M, int NC, int relu) {
    int tid = blockIdx.x * blockDim.x + threadIdx.x;
    int col = tid % NC;  // grid*block stride is a multiple of NC -> col fixed
    float mean = csum[col] / (float)M;
    float var = csq[col] / (float)M - mean * mean;
    float scale = g[col] * rsqrtf(var + 1e-5f);
    float shift = b[col] - mean * scale;
    size_t total = (size_t)M * NC;
    size_t stride = (size_t)gridDim.x * blockDim.x;
    for (size_t i = tid; i < total; i += stride) {
        float v = in[i] * scale + shift;
        if (relu) v = fmaxf(v, 0.f);
        out[i] = v;
    }
}

// ---- BN apply + segment-sum pooling over sorted batch (NC=128) ----------
__global__ __launch_bounds__(256) void bnrelu_pool_k(
        const float* __restrict__ in, float* __restrict__ out,  // out may be null
        const float* __restrict__ csum, const float* __restrict__ csq,
        const float* __restrict__ g, const float* __restrict__ b,
        const int* __restrict__ batch, float* __restrict__ pooled,
        int M, int relu) {
    int t = threadIdx.x;
    int col = t & (DH - 1);
    int r0 = blockIdx.x * 64 + (t >> 7) * 32;
    float mean = csum[col] / (float)M;
    float var = csq[col] / (float)M - mean * mean;
    float scale = g[col] * rsqrtf(var + 1e-5f);
    float shift = b[col] - mean * scale;
    int rend = r0 + 32; if (rend > M) rend = M;
    float accp = 0.f; int cur = -1;
    for (int r = r0; r < rend; r++) {
        float v = in[(size_t)r * DH + col] * scale + shift;
        if (relu) v = fmaxf(v, 0.f);
        if (out) out[(size_t)r * DH + col] = v;
        int bg = batch[r];
        if (bg != cur) {
            if (cur >= 0) atomicAdd(&pooled[(size_t)cur * DH + col], accp);
            cur = bg; accp = 0.f;
        }
        accp += v;
    }
    if (cur >= 0) atomicAdd(&pooled[(size_t)cur * DH + col], accp);
}

__global__ void addsmall_k(const float* __restrict__ a, const float* __restrict__ b,
                           float* __restrict__ o, int n) {
    int i = blockIdx.x * blockDim.x + threadIdx.x;
    if (i < n) o[i] = a[i] + b[i];
}

__global__ void finalout_k(const float* __restrict__ pooled2, const int* __restrict__ gcnt,
                           float* __restrict__ outp) {
    int i = blockIdx.x * blockDim.x + threadIdx.x;  // NG*DH
    float cnt = (float)gcnt[i >> 7];
    outp[i] = pooled2[i] / fmaxf(cnt, 1.0f);
}

// ------------------------------------------------------------------------
extern "C" void kernel_launch(void* const* d_in, const int* in_sizes, int n_in,
                              void* d_out, int out_size, void* d_ws, size_t ws_size,
                              hipStream_t stream) {
    const float* x      = (const float*)d_in[0];
    const int*   ei     = (const int*)d_in[1];
    const int*   batch  = (const int*)d_in[2];
    const float* vn_emb = (const float*)d_in[3];
    const float* c1_W1  = (const float*)d_in[4];
    const float* c1_b1  = (const float*)d_in[5];
    const float* c1_bng = (const float*)d_in[6];
    const float* c1_bnb = (const float*)d_in[7];
    const float* c1_W2  = (const float*)d_in[8];
    const float* c1_b2  = (const float*)d_in[9];
    const float* bn1_g  = (const float*)d_in[10];
    const float* bn1_b  = (const float*)d_in[11];
    const float* cW1    = (const float*)d_in[12];
    const float* cb1    = (const float*)d_in[13];
    const float* cbng   = (const float*)d_in[14];
    const float* cbnb   = (const float*)d_in[15];
    const float* cW2    = (const float*)d_in[16];
    const float* cb2    = (const float*)d_in[17];
    const float* bns_g  = (const float*)d_in[18];
    const float* bns_b  = (const float*)d_in[19];
    const float* vW1    = (const float*)d_in[20];
    const float* vb1    = (const float*)d_in[21];
    const float* vbn1_g = (const float*)d_in[22];
    const float* vbn1_b = (const float*)d_in[23];
    const float* vW2    = (const float*)d_in[24];
    const float* vb2    = (const float*)d_in[25];
    const float* vbn2_g = (const float*)d_in[26];
    const float* vbn2_b = (const float*)d_in[27];
    float* outp = (float*)d_out;

    char* w = (char*)d_ws;
    size_t off = 0;
    auto carve = [&](size_t bytes) -> void* {
        void* p = w + off; off = align256(off + bytes); return p;
    };
    // ---- zero-init region (one memset covers all of these) ----
    int*   degcnt  = (int*)carve((size_t)NN * 4);
    int*   gcnt    = (int*)carve((size_t)NG * 4);
    float* pooled  = (float*)carve((size_t)NG * DH * 4);
    float* pooled2 = (float*)carve((size_t)NG * DH * 4);
    float* stats   = (float*)carve(3072 * 4);
    size_t zbytes = off;
    // stats sub-layout
    float *sA[3], *qA[3], *sB[3], *qB[3];
    float* sp = stats;
    for (int i = 0; i < 3; i++) { sA[i] = sp; sp += 256; qA[i] = sp; sp += 256; }
    for (int i = 0; i < 3; i++) { sB[i] = sp; sp += 128; qB[i] = sp; sp += 128; }
    float* sV1 = sp; sp += 256; float* qV1 = sp; sp += 256;
    float* sV2 = sp; sp += 128; float* qV2 = sp; sp += 128;
    // ---- non-zeroed region ----
    int*   rowptr  = (int*)carve((size_t)(NN + 1) * 4);
    int*   fillpos = (int*)carve((size_t)NN * 4);
    int*   esrc    = (int*)carve((size_t)NE * 4);
    float* vfeat   = (float*)carve((size_t)NG * DH * 4);
    float* zin     = (float*)carve((size_t)NG * DH * 4);
    float* zbuf    = (float*)carve((size_t)NG * DH2 * 4);
    float* vraw    = (float*)carve((size_t)NG * DH * 4);
    float* bufA    = (float*)carve((size_t)NN * DH * 4);
    float* bufH    = (float*)carve((size_t)NN * DH * 4);
    float* bufB    = (float*)carve((size_t)NN * DH2 * 4);
    (void)ws_size; (void)in_sizes; (void)n_in; (void)out_size;

    const int GB64 = (NN + 63) / 64;  // 1563

    hipMemsetAsync(d_ws, 0, zbytes, stream);
    count_k<<<(NE + 255) / 256, 256, 0, stream>>>(ei, batch, degcnt, gcnt);
    scan_k<<<1, 1024, 0, stream>>>(degcnt, rowptr, fillpos);
    fill_k<<<(NE + 255) / 256, 256, 0, stream>>>(ei, fillpos, esrc);
    vinit_k<<<(NG * DH) / 256, 256, 0, stream>>>(vn_emb, vfeat);

    // ---- layer 1 ----
    agg_k<<<NN, DH, 0, stream>>>(x, rowptr, esrc, bufH);
    gemm_stats_k<128, 256><<<GB64, 256, 0, stream>>>(bufH, c1_W1, c1_b1, bufB, sA[0], qA[0], NN);
    bnrelu_k<<<1024, 256, 0, stream>>>(bufB, bufB, sA[0], qA[0], c1_bng, c1_bnb, NN, 256, 1);
    gemm_stats_k<256, 128><<<GB64, 128, 0, stream>>>(bufB, c1_W2, c1_b2, bufA, sB[0], qB[0], NN);
    bnrelu_k<<<1024, 256, 0, stream>>>(bufA, bufA, sB[0], qB[0], bn1_g, bn1_b, NN, 128, 1);

    // ---- layer 2 (i = 0) ----
    addvn_k<<<NN, DH, 0, stream>>>(bufA, vfeat, batch);
    agg_k<<<NN, DH, 0, stream>>>(bufA, rowptr, esrc, bufH);
    gemm_stats_k<128, 256><<<GB64, 256, 0, stream>>>(bufH, cW1, cb1, bufB, sA[1], qA[1], NN);
    bnrelu_k<<<1024, 256, 0, stream>>>(bufB, bufB, sA[1], qA[1], cbng, cbnb, NN, 256, 1);
    gemm_stats_k<256, 128><<<GB64, 128, 0, stream>>>(bufB, cW2, cb2, bufA, sB[1], qB[1], NN);
    bnrelu_pool_k<<<GB64, 256, 0, stream>>>(bufA, bufA, sB[1], qB[1], bns_g, bns_b,
                                            batch, pooled, NN, 1);

    // ---- virtual-node MLP ----
    addsmall_k<<<(NG * DH + 255) / 256, 256, 0, stream>>>(pooled, vfeat, zin, NG * DH);
    gemm_stats_k<128, 256><<<(NG + 63) / 64, 256, 0, stream>>>(zin, vW1, vb1, zbuf, sV1, qV1, NG);
    bnrelu_k<<<64, 256, 0, stream>>>(zbuf, zbuf, sV1, qV1, vbn1_g, vbn1_b, NG, 256, 1);
    gemm_stats_k<256, 128><<<(NG + 63) / 64, 128, 0, stream>>>(zbuf, vW2, vb2, vraw, sV2, qV2, NG);
    bnrelu_k<<<64, 256, 0, stream>>>(vraw, vfeat, sV2, qV2, vbn2_g, vbn2_b, NG, 128, 1);

    // ---- layer 3 (i = 1) ----
    addvn_k<<<NN, DH, 0, stream>>>(bufA, vfeat, batch);
    agg_k<<<NN, DH, 0, stream>>>(bufA, rowptr, esrc, bufH);
    gemm_stats_k<128, 256><<<GB64, 256, 0, stream>>>(bufH, cW1 + 128 * 256, cb1 + 256,
                                                     bufB, sA[2], qA[2], NN);
    bnrelu_k<<<1024, 256, 0, stream>>>(bufB, bufB, sA[2], qA[2], cbng + 256, cbnb + 256, NN, 256, 1);
    gemm_stats_k<256, 128><<<GB64, 128, 0, stream>>>(bufB, cW2 + 256 * 128, cb2 + 128,
                                                     bufA, sB[2], qB[2], NN);
    bnrelu_pool_k<<<GB64, 256, 0, stream>>>(bufA, nullptr, sB[2], qB[2], bns_g + 128, bns_b + 128,
                                            batch, pooled2, NN, 0);

    finalout_k<<<(NG * DH) / 256, 256, 0, stream>>>(pooled2, gcnt, outp);
}

// Round 3
// 1670.829 us; speedup vs baseline: 1.6971x; 1.6971x over previous
//
#include <hip/hip_runtime.h>

#define NN 100000
#define NE 1600000
#define NG 512
#define DH 128
#define DH2 256

typedef __attribute__((ext_vector_type(8))) _Float16 h8;  // 8 f16 (4 VGPRs)
typedef __attribute__((ext_vector_type(4))) float f4;     // MFMA C/D frag

static inline size_t align256(size_t x) { return (x + 255) & ~size_t(255); }

// ---- graph structure ----------------------------------------------------
__global__ void count_k(const int* __restrict__ ei, const int* __restrict__ batch,
                        int* __restrict__ deg, int* __restrict__ gcnt) {
    int i = blockIdx.x * blockDim.x + threadIdx.x;
    if (i < NE) atomicAdd(&deg[ei[NE + i]], 1);
    if (i < NN) atomicAdd(&gcnt[batch[i]], 1);
}

__global__ void scan_k(const int* __restrict__ deg, int* __restrict__ rowptr,
                       int* __restrict__ fillpos) {
    __shared__ int s[1024];
    int t = threadIdx.x;
    const int CH = (NN + 1023) / 1024;
    int beg = t * CH;
    int end = beg + CH; if (end > NN) end = NN;
    int sum = 0;
    for (int i = beg; i < end && i < NN; i++) sum += deg[i];
    s[t] = sum;
    __syncthreads();
    if (t == 0) {
        int run = 0;
        for (int i = 0; i < 1024; i++) { int v = s[i]; s[i] = run; run += v; }
    }
    __syncthreads();
    int run = s[t];
    for (int i = beg; i < end && i < NN; i++) {
        rowptr[i] = run; fillpos[i] = run; run += deg[i];
    }
    if (t == 1023) rowptr[NN] = run;
}

__global__ void fill_k(const int* __restrict__ ei, int* __restrict__ fillpos,
                       int* __restrict__ esrc) {
    int e = blockIdx.x * blockDim.x + threadIdx.x;
    if (e < NE) {
        int p = atomicAdd(&fillpos[ei[NE + e]], 1);
        esrc[p] = ei[e];
    }
}

// ---- small ops ----------------------------------------------------------
__global__ void vinit_k(const float* __restrict__ emb, float* __restrict__ vfeat) {
    int i = blockIdx.x * blockDim.x + threadIdx.x;  // NG*DH
    if (i < NG * DH) vfeat[i] = emb[i & (DH - 1)];
}

__global__ void zin_k(const float* __restrict__ pooled, const float* __restrict__ vf,
                      float* __restrict__ zb) {
    int i = blockIdx.x * blockDim.x + threadIdx.x;  // NG*DH
    if (i < NG * DH) zb[i] = pooled[i] + vf[i];
}

__global__ void addvn_k(float* __restrict__ x, const float* __restrict__ vfeat,
                        const int* __restrict__ batch) {
    int i = blockIdx.x * blockDim.x + threadIdx.x;  // NN*32 float4s
    if (i >= NN * 32) return;
    int row = i >> 5;
    int bg = batch[row];
    float4 u = ((float4*)x)[i];
    float4 v = ((const float4*)vfeat)[bg * 32 + (i & 31)];
    u.x += v.x; u.y += v.y; u.z += v.z; u.w += v.w;
    ((float4*)x)[i] = u;
}

__global__ void finalout_k(const float* __restrict__ pooled2, const int* __restrict__ gcnt,
                           float* __restrict__ outp) {
    int i = blockIdx.x * blockDim.x + threadIdx.x;
    if (i >= NG * DH) return;
    float cnt = (float)gcnt[i >> 7];
    outp[i] = pooled2[i] / fmaxf(cnt, 1.0f);
}

// ---- weight transpose+cast: W[K][N] f32 -> Wt[N][K] f16 -----------------
struct WPack {
    const float* w[8];
    _Float16* wt[8];
    int K[8];
    int N[8];
};
__global__ void wtrans_k(WPack p) {
    int id = blockIdx.z;
    const float* W = p.w[id];
    _Float16* Wt = p.wt[id];
    int K = p.K[id], N = p.N[id];
    int n0 = blockIdx.x * 32, k0 = blockIdx.y * 32;
    if (n0 >= N || k0 >= K) return;
    __shared__ float t[32][33];
    int tx = threadIdx.x & 31, ty = threadIdx.x >> 5;  // 256 thr: 8 rows
    for (int i = 0; i < 32; i += 8)
        t[ty + i][tx] = W[(size_t)(k0 + ty + i) * N + n0 + tx];
    __syncthreads();
    for (int i = 0; i < 32; i += 8)
        Wt[(size_t)(n0 + ty + i) * K + k0 + tx] = (_Float16)t[tx][ty + i];
}

// ---- aggregation: out[n] = in[n] + sum_j in[src_j]  (f32, wave/node) ----
__global__ __launch_bounds__(256) void agg_k(const float* __restrict__ xin,
                                             const int* __restrict__ rowptr,
                                             const int* __restrict__ esrc,
                                             float* __restrict__ out) {
    int wave = threadIdx.x >> 6, lane = threadIdx.x & 63;
    int node = blockIdx.x * 4 + wave;
    if (node >= NN) return;
    const float2* xr = (const float2*)xin;
    float2 self = xr[(size_t)node * 64 + lane];
    float a0 = self.x, a1 = self.y;
    int beg = rowptr[node], end = rowptr[node + 1];
    int j = beg;
    for (; j + 3 < end; j += 4) {
        int s0 = esrc[j], s1 = esrc[j + 1], s2 = esrc[j + 2], s3 = esrc[j + 3];
        float2 u0 = xr[(size_t)s0 * 64 + lane];
        float2 u1 = xr[(size_t)s1 * 64 + lane];
        float2 u2 = xr[(size_t)s2 * 64 + lane];
        float2 u3 = xr[(size_t)s3 * 64 + lane];
        a0 += u0.x + u1.x + u2.x + u3.x;
        a1 += u0.y + u1.y + u2.y + u3.y;
    }
    for (; j < end; j++) {
        float2 u = xr[(size_t)esrc[j] * 64 + lane];
        a0 += u.x; a1 += u.y;
    }
    float2 o; o.x = a0; o.y = a1;
    ((float2*)out)[(size_t)node * 64 + lane] = o;
}

// ---- MFMA GEMM: C[M x NCF] = A[M x K] @ W + bias, col sum/sumsq fused ---
// A row-major f32 (cast to f16 during LDS staging); Wt[NCF][K] f16.
// block tile 128x128, 4 waves 2x2, wave tile 64x64 = 4x4 frags of 16x16x32.
template <int K, int NCF>
__global__ __launch_bounds__(256, 2) void mgemm_k(
        const float* __restrict__ A, const _Float16* __restrict__ Wt,
        const float* __restrict__ bias, float* __restrict__ C,
        float* __restrict__ csum, float* __restrict__ csq, int M) {
    constexpr int BK = 128;
    constexpr int LDA = BK + 8;  // +16B pad: frag reads spread across bank groups
    __shared__ __align__(16) _Float16 As[128 * LDA];
    const int tid = threadIdx.x;
    const int lane = tid & 63;
    const int wave = tid >> 6;
    const int wr = wave & 1, wc = wave >> 1;
    const int lm = lane & 15, lq = lane >> 4;
    const int mB = blockIdx.x * 128;
    const int n0 = blockIdx.y * 128 + wc * 64;

    f4 acc[4][4];
#pragma unroll
    for (int i = 0; i < 4; i++)
#pragma unroll
        for (int j = 0; j < 4; j++) acc[i][j] = (f4){0.f, 0.f, 0.f, 0.f};

    const int sr = tid >> 4;         // staging row within 16-row group
    const int sc = (tid & 15) * 8;   // staging elem offset (8 elems = 2 float4)

    for (int kc = 0; kc < K; kc += BK) {
        if (kc) __syncthreads();
#pragma unroll
        for (int rr = 0; rr < 128; rr += 16) {
            int gr = mB + rr + sr; if (gr >= M) gr = M - 1;
            const float* src = A + (size_t)gr * K + kc + sc;
            float4 p = *(const float4*)src;
            float4 q = *(const float4*)(src + 4);
            h8 h = {(_Float16)p.x, (_Float16)p.y, (_Float16)p.z, (_Float16)p.w,
                    (_Float16)q.x, (_Float16)q.y, (_Float16)q.z, (_Float16)q.w};
            *(h8*)&As[(rr + sr) * LDA + sc] = h;
        }
        __syncthreads();
#pragma unroll
        for (int ks = 0; ks < BK / 32; ks++) {
            h8 af[4], bf[4];
#pragma unroll
            for (int t = 0; t < 4; t++) {
                af[t] = *(const h8*)&As[(wr * 64 + t * 16 + lm) * LDA + ks * 32 + lq * 8];
                bf[t] = *(const h8*)&Wt[(size_t)(n0 + t * 16 + lm) * K + kc + ks * 32 + lq * 8];
            }
#pragma unroll
            for (int i = 0; i < 4; i++)
#pragma unroll
                for (int j = 0; j < 4; j++)
                    acc[i][j] = __builtin_amdgcn_mfma_f32_16x16x32_f16(af[i], bf[j], acc[i][j], 0, 0, 0);
        }
    }

    // epilogue: bias, store f32, column stats
    float bv[4];
#pragma unroll
    for (int j = 0; j < 4; j++) bv[j] = bias[n0 + j * 16 + lm];
    float ls[4] = {0, 0, 0, 0}, lsq[4] = {0, 0, 0, 0};
    const int m0 = mB + wr * 64;
#pragma unroll
    for (int i = 0; i < 4; i++) {
#pragma unroll
        for (int j = 0; j < 4; j++) {
#pragma unroll
            for (int r = 0; r < 4; r++) {
                int row = m0 + i * 16 + lq * 4 + r;
                if (row < M) {
                    float v = acc[i][j][r] + bv[j];
                    C[(size_t)row * NCF + n0 + j * 16 + lm] = v;
                    ls[j] += v; lsq[j] += v * v;
                }
            }
        }
    }
#pragma unroll
    for (int j = 0; j < 4; j++) {
        float s = ls[j], q = lsq[j];
        s += __shfl_xor(s, 16); s += __shfl_xor(s, 32);
        q += __shfl_xor(q, 16); q += __shfl_xor(q, 32);
        if (lq == 0) {
            atomicAdd(&csum[n0 + j * 16 + lm], s);
            atomicAdd(&csq[n0 + j * 16 + lm], q);
        }
    }
}

// ---- BN apply (+relu, +optional vn-add after relu), f32 x4 vectorized ---
template <int NC>
__global__ void bnrelu_k(const float* __restrict__ in, float* __restrict__ out,
                         const float* __restrict__ csum, const float* __restrict__ csq,
                         const float* __restrict__ g, const float* __restrict__ b,
                         const float* __restrict__ vfeat, const int* __restrict__ batch,
                         int M, int relu) {
    constexpr int PER = NC / 4;  // float4s per row
    int tid = blockIdx.x * blockDim.x + threadIdx.x;
    int c4 = tid % PER;          // stride is a multiple of PER -> col fixed
    int c0 = c4 * 4;
    float invM = 1.0f / (float)M;
    float sc[4], sh[4];
#pragma unroll
    for (int e = 0; e < 4; e++) {
        int col = c0 + e;
        float mean = csum[col] * invM;
        float var = csq[col] * invM - mean * mean;
        sc[e] = g[col] * rsqrtf(var + 1e-5f);
        sh[e] = b[col] - mean * sc[e];
    }
    int total = M * PER;
    int stride = gridDim.x * blockDim.x;
    for (int i = tid; i < total; i += stride) {
        int row = i / PER;
        float4 u = ((const float4*)in)[i];
        float v[4] = {u.x, u.y, u.z, u.w};
        float4 w = {0.f, 0.f, 0.f, 0.f};
        if (vfeat) w = ((const float4*)vfeat)[batch[row] * PER + c4];
#pragma unroll
        for (int e = 0; e < 4; e++) {
            float vv = v[e] * sc[e] + sh[e];
            if (relu) vv = fmaxf(vv, 0.f);
            v[e] = vv;
        }
        float4 o; o.x = v[0] + w.x; o.y = v[1] + w.y; o.z = v[2] + w.z; o.w = v[3] + w.w;
        ((float4*)out)[i] = o;
    }
}

// ---- BN apply + segment-sum pool over sorted batch (NC=128, f32) --------
__global__ __launch_bounds__(256) void bnpool_k(
        const float* __restrict__ in, float* __restrict__ out,
        const float* __restrict__ csum, const float* __restrict__ csq,
        const float* __restrict__ g, const float* __restrict__ b,
        const int* __restrict__ batch, float* __restrict__ pooled,
        int M, int relu) {
    int t = threadIdx.x;
    int c0 = (t & 63) * 2;
    int r0 = blockIdx.x * 128 + (t >> 6) * 32;
    float invM = 1.0f / (float)M;
    float mean0 = csum[c0] * invM;
    float var0 = csq[c0] * invM - mean0 * mean0;
    float s0 = g[c0] * rsqrtf(var0 + 1e-5f), h0 = b[c0] - mean0 * s0;
    float mean1 = csum[c0 + 1] * invM;
    float var1 = csq[c0 + 1] * invM - mean1 * mean1;
    float s1 = g[c0 + 1] * rsqrtf(var1 + 1e-5f), h1 = b[c0 + 1] - mean1 * s1;
    int rend = r0 + 32; if (rend > M) rend = M;
    float a0 = 0.f, a1 = 0.f; int cur = -1;
    for (int r = r0; r < rend; r++) {
        float2 u = ((const float2*)in)[(size_t)r * 64 + (c0 >> 1)];
        float v0 = u.x * s0 + h0;
        float v1 = u.y * s1 + h1;
        if (relu) { v0 = fmaxf(v0, 0.f); v1 = fmaxf(v1, 0.f); }
        if (out) { float2 o; o.x = v0; o.y = v1; ((float2*)out)[(size_t)r * 64 + (c0 >> 1)] = o; }
        int bg = batch[r];
        if (bg != cur) {
            if (cur >= 0) {
                atomicAdd(&pooled[(size_t)cur * DH + c0], a0);
                atomicAdd(&pooled[(size_t)cur * DH + c0 + 1], a1);
            }
            cur = bg; a0 = 0.f; a1 = 0.f;
        }
        a0 += v0; a1 += v1;
    }
    if (cur >= 0) {
        atomicAdd(&pooled[(size_t)cur * DH + c0], a0);
        atomicAdd(&pooled[(size_t)cur * DH + c0 + 1], a1);
    }
}

// ------------------------------------------------------------------------
extern "C" void kernel_launch(void* const* d_in, const int* in_sizes, int n_in,
                              void* d_out, int out_size, void* d_ws, size_t ws_size,
                              hipStream_t stream) {
    const float* x      = (const float*)d_in[0];
    const int*   ei     = (const int*)d_in[1];
    const int*   batch  = (const int*)d_in[2];
    const float* vn_emb = (const float*)d_in[3];
    const float* c1_W1  = (const float*)d_in[4];
    const float* c1_b1  = (const float*)d_in[5];
    const float* c1_bng = (const float*)d_in[6];
    const float* c1_bnb = (const float*)d_in[7];
    const float* c1_W2  = (const float*)d_in[8];
    const float* c1_b2  = (const float*)d_in[9];
    const float* bn1_g  = (const float*)d_in[10];
    const float* bn1_b  = (const float*)d_in[11];
    const float* cW1    = (const float*)d_in[12];
    const float* cb1    = (const float*)d_in[13];
    const float* cbng   = (const float*)d_in[14];
    const float* cbnb   = (const float*)d_in[15];
    const float* cW2    = (const float*)d_in[16];
    const float* cb2    = (const float*)d_in[17];
    const float* bns_g  = (const float*)d_in[18];
    const float* bns_b  = (const float*)d_in[19];
    const float* vW1    = (const float*)d_in[20];
    const float* vb1    = (const float*)d_in[21];
    const float* vbn1_g = (const float*)d_in[22];
    const float* vbn1_b = (const float*)d_in[23];
    const float* vW2    = (const float*)d_in[24];
    const float* vb2    = (const float*)d_in[25];
    const float* vbn2_g = (const float*)d_in[26];
    const float* vbn2_b = (const float*)d_in[27];
    float* outp = (float*)d_out;
    (void)in_sizes; (void)n_in; (void)out_size; (void)ws_size;

    char* w = (char*)d_ws;
    size_t off = 0;
    auto carve = [&](size_t bytes) -> void* {
        void* p = w + off; off = align256(off + bytes); return p;
    };
    // zero-init region
    int*   degcnt  = (int*)carve((size_t)NN * 4);
    int*   gcnt    = (int*)carve((size_t)NG * 4);
    float* pooled  = (float*)carve((size_t)NG * DH * 4);
    float* pooled2 = (float*)carve((size_t)NG * DH * 4);
    float* stats   = (float*)carve(3072 * 4);
    size_t zbytes = off;
    float *sA[3], *qA[3], *sB[3], *qB[3];
    float* sp = stats;
    for (int i = 0; i < 3; i++) { sA[i] = sp; sp += 256; qA[i] = sp; sp += 256; }
    for (int i = 0; i < 3; i++) { sB[i] = sp; sp += 128; qB[i] = sp; sp += 128; }
    float* sV1 = sp; sp += 256; float* qV1 = sp; sp += 256;
    float* sV2 = sp; sp += 128; float* qV2 = sp; sp += 128;
    // non-zeroed region
    int*   rowptr  = (int*)carve((size_t)(NN + 1) * 4);
    int*   fillpos = (int*)carve((size_t)NN * 4);
    int*   esrc    = (int*)carve((size_t)NE * 4);
    float* vfeat   = (float*)carve((size_t)NG * DH * 4);
    float* zin     = (float*)carve((size_t)NG * DH * 4);
    float* zb      = (float*)carve((size_t)NG * DH2 * 4);
    float* vraw    = (float*)carve((size_t)NG * DH * 4);
    float* hb      = (float*)carve((size_t)NN * DH * 4);
    float* b1      = (float*)carve((size_t)NN * DH2 * 4);
    float* abuf    = (float*)carve((size_t)NN * DH * 4);
    _Float16* Wt[8];
    // shapes: [0]=c1_W1 128x256, [1]=c1_W2 256x128, [2]=cW1_0, [3]=cW2_0,
    //         [4]=cW1_1, [5]=cW2_1, [6]=vW1, [7]=vW2
    for (int i = 0; i < 8; i++) Wt[i] = (_Float16*)carve((size_t)DH * DH2 * 2);

    WPack wp;
    wp.w[0] = c1_W1;            wp.K[0] = 128; wp.N[0] = 256;
    wp.w[1] = c1_W2;            wp.K[1] = 256; wp.N[1] = 128;
    wp.w[2] = cW1;              wp.K[2] = 128; wp.N[2] = 256;
    wp.w[3] = cW2;              wp.K[3] = 256; wp.N[3] = 128;
    wp.w[4] = cW1 + 128 * 256;  wp.K[4] = 128; wp.N[4] = 256;
    wp.w[5] = cW2 + 256 * 128;  wp.K[5] = 256; wp.N[5] = 128;
    wp.w[6] = vW1;              wp.K[6] = 128; wp.N[6] = 256;
    wp.w[7] = vW2;              wp.K[7] = 256; wp.N[7] = 128;
    for (int i = 0; i < 8; i++) wp.wt[i] = Wt[i];

    const int GB = (NN + 127) / 128;  // 782
    dim3 gemmA(GB, 2), gemmB(GB, 1);  // NC=256 / NC=128

    hipMemsetAsync(d_ws, 0, zbytes, stream);
    count_k<<<(NE + 255) / 256, 256, 0, stream>>>(ei, batch, degcnt, gcnt);
    scan_k<<<1, 1024, 0, stream>>>(degcnt, rowptr, fillpos);
    fill_k<<<(NE + 255) / 256, 256, 0, stream>>>(ei, fillpos, esrc);
    wtrans_k<<<dim3(8, 8, 8), 256, 0, stream>>>(wp);
    vinit_k<<<(NG * DH + 255) / 256, 256, 0, stream>>>(vn_emb, vfeat);

    // ---- layer 1 ----
    agg_k<<<NN / 4, 256, 0, stream>>>(x, rowptr, esrc, hb);
    mgemm_k<128, 256><<<gemmA, 256, 0, stream>>>(hb, Wt[0], c1_b1, b1, sA[0], qA[0], NN);
    bnrelu_k<256><<<2048, 256, 0, stream>>>(b1, b1, sA[0], qA[0], c1_bng, c1_bnb,
                                            nullptr, nullptr, NN, 1);
    mgemm_k<256, 128><<<gemmB, 256, 0, stream>>>(b1, Wt[1], c1_b2, abuf, sB[0], qB[0], NN);
    // bn1 + relu + fused vn-add (layer2 input = relu(bn(...)) + vfeat0[batch])
    bnrelu_k<128><<<2048, 256, 0, stream>>>(abuf, abuf, sB[0], qB[0], bn1_g, bn1_b,
                                            vfeat, batch, NN, 1);

    // ---- layer 2 ----
    agg_k<<<NN / 4, 256, 0, stream>>>(abuf, rowptr, esrc, hb);
    mgemm_k<128, 256><<<gemmA, 256, 0, stream>>>(hb, Wt[2], cb1, b1, sA[1], qA[1], NN);
    bnrelu_k<256><<<2048, 256, 0, stream>>>(b1, b1, sA[1], qA[1], cbng, cbnb,
                                            nullptr, nullptr, NN, 1);
    mgemm_k<256, 128><<<gemmB, 256, 0, stream>>>(b1, Wt[3], cb2, abuf, sB[1], qB[1], NN);
    bnpool_k<<<GB, 256, 0, stream>>>(abuf, abuf, sB[1], qB[1], bns_g, bns_b,
                                     batch, pooled, NN, 1);

    // ---- virtual-node MLP (M = 512) ----
    zin_k<<<(NG * DH + 255) / 256, 256, 0, stream>>>(pooled, vfeat, zin);
    mgemm_k<128, 256><<<dim3(4, 2), 256, 0, stream>>>(zin, Wt[6], vb1, zb, sV1, qV1, NG);
    bnrelu_k<256><<<64, 256, 0, stream>>>(zb, zb, sV1, qV1, vbn1_g, vbn1_b,
                                          nullptr, nullptr, NG, 1);
    mgemm_k<256, 128><<<dim3(4, 1), 256, 0, stream>>>(zb, Wt[7], vb2, vraw, sV2, qV2, NG);
    bnrelu_k<128><<<32, 256, 0, stream>>>(vraw, vfeat, sV2, qV2, vbn2_g, vbn2_b,
                                          nullptr, nullptr, NG, 1);

    // ---- layer 3 ----
    addvn_k<<<(NN * 32 + 255) / 256, 256, 0, stream>>>(abuf, vfeat, batch);
    agg_k<<<NN / 4, 256, 0, stream>>>(abuf, rowptr, esrc, hb);
    mgemm_k<128, 256><<<gemmA, 256, 0, stream>>>(hb, Wt[4], cb1 + 256, b1, sA[2], qA[2], NN);
    bnrelu_k<256><<<2048, 256, 0, stream>>>(b1, b1, sA[2], qA[2], cbng + 256, cbnb + 256,
                                            nullptr, nullptr, NN, 1);
    mgemm_k<256, 128><<<gemmB, 256, 0, stream>>>(b1, Wt[5], cb2 + 128, abuf, sB[2], qB[2], NN);
    bnpool_k<<<GB, 256, 0, stream>>>(abuf, nullptr, sB[2], qB[2], bns_g + 128, bns_b + 128,
                                     batch, pooled2, NN, 0);

    finalout_k<<<(NG * DH + 255) / 256, 256, 0, stream>>>(pooled2, gcnt, outp);
}

// Round 4
// 1441.917 us; speedup vs baseline: 1.9666x; 1.1588x over previous
//
#include <hip/hip_runtime.h>

#define NN 100000
#define NE 1600000
#define NG 512
#define DH 128
#define DH2 256
#define SCB 98  // ceil(NN / 1024)

typedef __attribute__((ext_vector_type(8))) _Float16 h8;  // 8 f16 (4 VGPRs)
typedef __attribute__((ext_vector_type(4))) float f4;     // MFMA C/D frag

static inline size_t align256(size_t x) { return (x + 255) & ~size_t(255); }

// ---- graph structure ----------------------------------------------------
__global__ void count_k(const int* __restrict__ ei, const int* __restrict__ batch,
                        int* __restrict__ deg, int* __restrict__ gcnt) {
    int i = blockIdx.x * blockDim.x + threadIdx.x;
    if (i < NE) atomicAdd(&deg[ei[NE + i]], 1);
    if (i < NN) atomicAdd(&gcnt[batch[i]], 1);
}

// 3-kernel device-wide exclusive scan of deg[NN] -> rowptr/fillpos
__global__ __launch_bounds__(256) void scan1_k(const int* __restrict__ deg,
                                               int* __restrict__ part) {
    int i0 = blockIdx.x * 1024 + threadIdx.x * 4;
    int s = 0;
    if (i0 < NN) {  // NN % 4 == 0, int4 fully in-range
        int4 v = *(const int4*)(deg + i0);
        s = v.x + v.y + v.z + v.w;
    }
#pragma unroll
    for (int o = 1; o < 64; o <<= 1) s += __shfl_xor(s, o);
    __shared__ int ws[4];
    if ((threadIdx.x & 63) == 0) ws[threadIdx.x >> 6] = s;
    __syncthreads();
    if (threadIdx.x == 0) part[blockIdx.x] = ws[0] + ws[1] + ws[2] + ws[3];
}

__global__ void scan2_k(int* __restrict__ part, int* __restrict__ rowptr) {
    if (threadIdx.x == 0) {
        int run = 0;
        for (int i = 0; i < SCB; i++) { int v = part[i]; part[i] = run; run += v; }
        rowptr[NN] = run;
    }
}

__global__ __launch_bounds__(256) void scan3_k(const int* __restrict__ deg,
                                               const int* __restrict__ part,
                                               int* __restrict__ rowptr,
                                               int* __restrict__ fillpos) {
    int t = threadIdx.x;
    int i0 = blockIdx.x * 1024 + t * 4;
    int4 v = {0, 0, 0, 0};
    if (i0 < NN) v = *(const int4*)(deg + i0);
    int s = v.x + v.y + v.z + v.w;
    __shared__ int sc[256];
    sc[t] = s;
    __syncthreads();
    for (int o = 1; o < 256; o <<= 1) {
        int add = (t >= o) ? sc[t - o] : 0;
        __syncthreads();
        sc[t] += add;
        __syncthreads();
    }
    int excl = (t ? sc[t - 1] : 0) + part[blockIdx.x];
    if (i0 < NN) {
        int4 r;
        r.x = excl;
        r.y = excl + v.x;
        r.z = excl + v.x + v.y;
        r.w = excl + v.x + v.y + v.z;
        *(int4*)(rowptr + i0) = r;
        *(int4*)(fillpos + i0) = r;
    }
}

__global__ void fill_k(const int* __restrict__ ei, int* __restrict__ fillpos,
                       int* __restrict__ esrc) {
    int e = blockIdx.x * blockDim.x + threadIdx.x;
    if (e < NE) {
        int p = atomicAdd(&fillpos[ei[NE + e]], 1);
        esrc[p] = ei[e];
    }
}

// ---- small ops ----------------------------------------------------------
__global__ void vinit_k(const float* __restrict__ emb, float* __restrict__ vfeat) {
    int i = blockIdx.x * blockDim.x + threadIdx.x;  // NG*DH
    if (i < NG * DH) vfeat[i] = emb[i & (DH - 1)];
}

__global__ void zin_k(const float* __restrict__ pooled, const float* __restrict__ vf,
                      float* __restrict__ zb) {
    int i = blockIdx.x * blockDim.x + threadIdx.x;  // NG*DH
    if (i < NG * DH) zb[i] = pooled[i] + vf[i];
}

__global__ void addvn_k(float* __restrict__ x, const float* __restrict__ vfeat,
                        const int* __restrict__ batch) {
    int i = blockIdx.x * blockDim.x + threadIdx.x;  // NN*32 float4s
    if (i >= NN * 32) return;
    int row = i >> 5;
    int bg = batch[row];
    float4 u = ((float4*)x)[i];
    float4 v = ((const float4*)vfeat)[bg * 32 + (i & 31)];
    u.x += v.x; u.y += v.y; u.z += v.z; u.w += v.w;
    ((float4*)x)[i] = u;
}

__global__ void finalout_k(const float* __restrict__ pooled2, const int* __restrict__ gcnt,
                           float* __restrict__ outp) {
    int i = blockIdx.x * blockDim.x + threadIdx.x;
    if (i >= NG * DH) return;
    float cnt = (float)gcnt[i >> 7];
    outp[i] = pooled2[i] / fmaxf(cnt, 1.0f);
}

// ---- weight transpose+cast: W[K][N] f32 -> Wt[N][K] f16 -----------------
struct WPack {
    const float* w[8];
    _Float16* wt[8];
    int K[8];
    int N[8];
};
__global__ void wtrans_k(WPack p) {
    int id = blockIdx.z;
    const float* W = p.w[id];
    _Float16* Wt = p.wt[id];
    int K = p.K[id], N = p.N[id];
    int n0 = blockIdx.x * 32, k0 = blockIdx.y * 32;
    if (n0 >= N || k0 >= K) return;
    __shared__ float t[32][33];
    int tx = threadIdx.x & 31, ty = threadIdx.x >> 5;  // 256 thr: 8 rows
    for (int i = 0; i < 32; i += 8)
        t[ty + i][tx] = W[(size_t)(k0 + ty + i) * N + n0 + tx];
    __syncthreads();
    for (int i = 0; i < 32; i += 8)
        Wt[(size_t)(n0 + ty + i) * K + k0 + tx] = (_Float16)t[tx][ty + i];
}

// ---- aggregation: out[n] = in[n] + sum_j in[src_j]  (f32, wave/node) ----
__global__ __launch_bounds__(256) void agg_k(const float* __restrict__ xin,
                                             const int* __restrict__ rowptr,
                                             const int* __restrict__ esrc,
                                             float* __restrict__ out) {
    int wave = threadIdx.x >> 6, lane = threadIdx.x & 63;
    int node = blockIdx.x * 4 + wave;
    if (node >= NN) return;
    const float2* xr = (const float2*)xin;
    float2 self = xr[(size_t)node * 64 + lane];
    float a0 = self.x, a1 = self.y;
    int beg = rowptr[node], end = rowptr[node + 1];
    int j = beg;
    for (; j + 3 < end; j += 4) {
        int s0 = esrc[j], s1 = esrc[j + 1], s2 = esrc[j + 2], s3 = esrc[j + 3];
        float2 u0 = xr[(size_t)s0 * 64 + lane];
        float2 u1 = xr[(size_t)s1 * 64 + lane];
        float2 u2 = xr[(size_t)s2 * 64 + lane];
        float2 u3 = xr[(size_t)s3 * 64 + lane];
        a0 += u0.x + u1.x + u2.x + u3.x;
        a1 += u0.y + u1.y + u2.y + u3.y;
    }
    for (; j < end; j++) {
        float2 u = xr[(size_t)esrc[j] * 64 + lane];
        a0 += u.x; a1 += u.y;
    }
    float2 o; o.x = a0; o.y = a1;
    ((float2*)out)[(size_t)node * 64 + lane] = o;
}

// ---- MFMA GEMM: C[M x NCF] = A[M x K] @ W + bias, col sum/sumsq fused ---
// A row-major f32 (cast to f16 during LDS staging); Wt[NCF][K] f16.
// block tile 128x128, 4 waves 2x2, wave tile 64x64 = 4x4 frags of 16x16x32.
template <int K, int NCF>
__global__ __launch_bounds__(256, 2) void mgemm_k(
        const float* __restrict__ A, const _Float16* __restrict__ Wt,
        const float* __restrict__ bias, float* __restrict__ C,
        float* __restrict__ csum, float* __restrict__ csq, int M) {
    constexpr int BK = 128;
    constexpr int LDA = BK + 8;  // +16B pad: frag reads spread across bank groups
    __shared__ __align__(16) _Float16 As[128 * LDA];
    const int tid = threadIdx.x;
    const int lane = tid & 63;
    const int wave = tid >> 6;
    const int wr = wave & 1, wc = wave >> 1;
    const int lm = lane & 15, lq = lane >> 4;
    const int mB = blockIdx.x * 128;
    const int n0 = blockIdx.y * 128 + wc * 64;

    f4 acc[4][4];
#pragma unroll
    for (int i = 0; i < 4; i++)
#pragma unroll
        for (int j = 0; j < 4; j++) acc[i][j] = (f4){0.f, 0.f, 0.f, 0.f};

    const int sr = tid >> 4;         // staging row within 16-row group
    const int sc = (tid & 15) * 8;   // staging elem offset (8 elems = 2 float4)

    for (int kc = 0; kc < K; kc += BK) {
        if (kc) __syncthreads();
#pragma unroll
        for (int rr = 0; rr < 128; rr += 16) {
            int gr = mB + rr + sr; if (gr >= M) gr = M - 1;
            const float* src = A + (size_t)gr * K + kc + sc;
            float4 p = *(const float4*)src;
            float4 q = *(const float4*)(src + 4);
            h8 h = {(_Float16)p.x, (_Float16)p.y, (_Float16)p.z, (_Float16)p.w,
                    (_Float16)q.x, (_Float16)q.y, (_Float16)q.z, (_Float16)q.w};
            *(h8*)&As[(rr + sr) * LDA + sc] = h;
        }
        __syncthreads();
#pragma unroll
        for (int ks = 0; ks < BK / 32; ks++) {
            h8 af[4], bf[4];
#pragma unroll
            for (int t = 0; t < 4; t++) {
                af[t] = *(const h8*)&As[(wr * 64 + t * 16 + lm) * LDA + ks * 32 + lq * 8];
                bf[t] = *(const h8*)&Wt[(size_t)(n0 + t * 16 + lm) * K + kc + ks * 32 + lq * 8];
            }
#pragma unroll
            for (int i = 0; i < 4; i++)
#pragma unroll
                for (int j = 0; j < 4; j++)
                    acc[i][j] = __builtin_amdgcn_mfma_f32_16x16x32_f16(af[i], bf[j], acc[i][j], 0, 0, 0);
        }
    }

    // epilogue: bias, store f32, column stats
    float bv[4];
#pragma unroll
    for (int j = 0; j < 4; j++) bv[j] = bias[n0 + j * 16 + lm];
    float ls[4] = {0, 0, 0, 0}, lsq[4] = {0, 0, 0, 0};
    const int m0 = mB + wr * 64;
#pragma unroll
    for (int i = 0; i < 4; i++) {
#pragma unroll
        for (int j = 0; j < 4; j++) {
#pragma unroll
            for (int r = 0; r < 4; r++) {
                int row = m0 + i * 16 + lq * 4 + r;
                if (row < M) {
                    float v = acc[i][j][r] + bv[j];
                    C[(size_t)row * NCF + n0 + j * 16 + lm] = v;
                    ls[j] += v; lsq[j] += v * v;
                }
            }
        }
    }
#pragma unroll
    for (int j = 0; j < 4; j++) {
        float s = ls[j], q = lsq[j];
        s += __shfl_xor(s, 16); s += __shfl_xor(s, 32);
        q += __shfl_xor(q, 16); q += __shfl_xor(q, 32);
        if (lq == 0) {
            atomicAdd(&csum[n0 + j * 16 + lm], s);
            atomicAdd(&csq[n0 + j * 16 + lm], q);
        }
    }
}

// ---- BN apply (+relu, +optional vn-add after relu), f32 x4 vectorized ---
template <int NC>
__global__ void bnrelu_k(const float* __restrict__ in, float* __restrict__ out,
                         const float* __restrict__ csum, const float* __restrict__ csq,
                         const float* __restrict__ g, const float* __restrict__ b,
                         const float* __restrict__ vfeat, const int* __restrict__ batch,
                         int M, int relu) {
    constexpr int PER = NC / 4;  // float4s per row
    int tid = blockIdx.x * blockDim.x + threadIdx.x;
    int c4 = tid % PER;          // stride is a multiple of PER -> col fixed
    int c0 = c4 * 4;
    float invM = 1.0f / (float)M;
    float sc[4], sh[4];
#pragma unroll
    for (int e = 0; e < 4; e++) {
        int col = c0 + e;
        float mean = csum[col] * invM;
        float var = csq[col] * invM - mean * mean;
        sc[e] = g[col] * rsqrtf(var + 1e-5f);
        sh[e] = b[col] - mean * sc[e];
    }
    int total = M * PER;
    int stride = gridDim.x * blockDim.x;
    for (int i = tid; i < total; i += stride) {
        int row = i / PER;
        float4 u = ((const float4*)in)[i];
        float v[4] = {u.x, u.y, u.z, u.w};
        float4 w = {0.f, 0.f, 0.f, 0.f};
        if (vfeat) w = ((const float4*)vfeat)[batch[row] * PER + c4];
#pragma unroll
        for (int e = 0; e < 4; e++) {
            float vv = v[e] * sc[e] + sh[e];
            if (relu) vv = fmaxf(vv, 0.f);
            v[e] = vv;
        }
        float4 o; o.x = v[0] + w.x; o.y = v[1] + w.y; o.z = v[2] + w.z; o.w = v[3] + w.w;
        ((float4*)out)[i] = o;
    }
}

// ---- BN apply + segment-sum pool over sorted batch (NC=128, f32) --------
__global__ __launch_bounds__(256) void bnpool_k(
        const float* __restrict__ in, float* __restrict__ out,
        const float* __restrict__ csum, const float* __restrict__ csq,
        const float* __restrict__ g, const float* __restrict__ b,
        const int* __restrict__ batch, float* __restrict__ pooled,
        int M, int relu) {
    int t = threadIdx.x;
    int c0 = (t & 63) * 2;
    int r0 = blockIdx.x * 128 + (t >> 6) * 32;
    float invM = 1.0f / (float)M;
    float mean0 = csum[c0] * invM;
    float var0 = csq[c0] * invM - mean0 * mean0;
    float s0 = g[c0] * rsqrtf(var0 + 1e-5f), h0 = b[c0] - mean0 * s0;
    float mean1 = csum[c0 + 1] * invM;
    float var1 = csq[c0 + 1] * invM - mean1 * mean1;
    float s1 = g[c0 + 1] * rsqrtf(var1 + 1e-5f), h1 = b[c0 + 1] - mean1 * s1;
    int rend = r0 + 32; if (rend > M) rend = M;
    float a0 = 0.f, a1 = 0.f; int cur = -1;
    for (int r = r0; r < rend; r++) {
        float2 u = ((const float2*)in)[(size_t)r * 64 + (c0 >> 1)];
        float v0 = u.x * s0 + h0;
        float v1 = u.y * s1 + h1;
        if (relu) { v0 = fmaxf(v0, 0.f); v1 = fmaxf(v1, 0.f); }
        if (out) { float2 o; o.x = v0; o.y = v1; ((float2*)out)[(size_t)r * 64 + (c0 >> 1)] = o; }
        int bg = batch[r];
        if (bg != cur) {
            if (cur >= 0) {
                atomicAdd(&pooled[(size_t)cur * DH + c0], a0);
                atomicAdd(&pooled[(size_t)cur * DH + c0 + 1], a1);
            }
            cur = bg; a0 = 0.f; a1 = 0.f;
        }
        a0 += v0; a1 += v1;
    }
    if (cur >= 0) {
        atomicAdd(&pooled[(size_t)cur * DH + c0], a0);
        atomicAdd(&pooled[(size_t)cur * DH + c0 + 1], a1);
    }
}

// ------------------------------------------------------------------------
extern "C" void kernel_launch(void* const* d_in, const int* in_sizes, int n_in,
                              void* d_out, int out_size, void* d_ws, size_t ws_size,
                              hipStream_t stream) {
    const float* x      = (const float*)d_in[0];
    const int*   ei     = (const int*)d_in[1];
    const int*   batch  = (const int*)d_in[2];
    const float* vn_emb = (const float*)d_in[3];
    const float* c1_W1  = (const float*)d_in[4];
    const float* c1_b1  = (const float*)d_in[5];
    const float* c1_bng = (const float*)d_in[6];
    const float* c1_bnb = (const float*)d_in[7];
    const float* c1_W2  = (const float*)d_in[8];
    const float* c1_b2  = (const float*)d_in[9];
    const float* bn1_g  = (const float*)d_in[10];
    const float* bn1_b  = (const float*)d_in[11];
    const float* cW1    = (const float*)d_in[12];
    const float* cb1    = (const float*)d_in[13];
    const float* cbng   = (const float*)d_in[14];
    const float* cbnb   = (const float*)d_in[15];
    const float* cW2    = (const float*)d_in[16];
    const float* cb2    = (const float*)d_in[17];
    const float* bns_g  = (const float*)d_in[18];
    const float* bns_b  = (const float*)d_in[19];
    const float* vW1    = (const float*)d_in[20];
    const float* vb1    = (const float*)d_in[21];
    const float* vbn1_g = (const float*)d_in[22];
    const float* vbn1_b = (const float*)d_in[23];
    const float* vW2    = (const float*)d_in[24];
    const float* vb2    = (const float*)d_in[25];
    const float* vbn2_g = (const float*)d_in[26];
    const float* vbn2_b = (const float*)d_in[27];
    float* outp = (float*)d_out;
    (void)in_sizes; (void)n_in; (void)out_size; (void)ws_size;

    char* w = (char*)d_ws;
    size_t off = 0;
    auto carve = [&](size_t bytes) -> void* {
        void* p = w + off; off = align256(off + bytes); return p;
    };
    // zero-init region
    int*   degcnt  = (int*)carve((size_t)NN * 4);
    int*   gcnt    = (int*)carve((size_t)NG * 4);
    float* pooled  = (float*)carve((size_t)NG * DH * 4);
    float* pooled2 = (float*)carve((size_t)NG * DH * 4);
    float* stats   = (float*)carve(3072 * 4);
    size_t zbytes = off;
    float *sA[3], *qA[3], *sB[3], *qB[3];
    float* sp = stats;
    for (int i = 0; i < 3; i++) { sA[i] = sp; sp += 256; qA[i] = sp; sp += 256; }
    for (int i = 0; i < 3; i++) { sB[i] = sp; sp += 128; qB[i] = sp; sp += 128; }
    float* sV1 = sp; sp += 256; float* qV1 = sp; sp += 256;
    float* sV2 = sp; sp += 128; float* qV2 = sp; sp += 128;
    // non-zeroed region
    int*   rowptr  = (int*)carve((size_t)(NN + 1) * 4);
    int*   fillpos = (int*)carve((size_t)NN * 4);
    int*   esrc    = (int*)carve((size_t)NE * 4);
    int*   part    = (int*)carve((size_t)SCB * 4);
    float* vfeat   = (float*)carve((size_t)NG * DH * 4);
    float* zin     = (float*)carve((size_t)NG * DH * 4);
    float* zb      = (float*)carve((size_t)NG * DH2 * 4);
    float* vraw    = (float*)carve((size_t)NG * DH * 4);
    float* hb      = (float*)carve((size_t)NN * DH * 4);
    float* b1      = (float*)carve((size_t)NN * DH2 * 4);
    float* abuf    = (float*)carve((size_t)NN * DH * 4);
    _Float16* Wt[8];
    // shapes: [0]=c1_W1 128x256, [1]=c1_W2 256x128, [2]=cW1_0, [3]=cW2_0,
    //         [4]=cW1_1, [5]=cW2_1, [6]=vW1, [7]=vW2
    for (int i = 0; i < 8; i++) Wt[i] = (_Float16*)carve((size_t)DH * DH2 * 2);

    WPack wp;
    wp.w[0] = c1_W1;            wp.K[0] = 128; wp.N[0] = 256;
    wp.w[1] = c1_W2;            wp.K[1] = 256; wp.N[1] = 128;
    wp.w[2] = cW1;              wp.K[2] = 128; wp.N[2] = 256;
    wp.w[3] = cW2;              wp.K[3] = 256; wp.N[3] = 128;
    wp.w[4] = cW1 + 128 * 256;  wp.K[4] = 128; wp.N[4] = 256;
    wp.w[5] = cW2 + 256 * 128;  wp.K[5] = 256; wp.N[5] = 128;
    wp.w[6] = vW1;              wp.K[6] = 128; wp.N[6] = 256;
    wp.w[7] = vW2;              wp.K[7] = 256; wp.N[7] = 128;
    for (int i = 0; i < 8; i++) wp.wt[i] = Wt[i];

    const int GB = (NN + 127) / 128;  // 782
    dim3 gemmA(GB, 2), gemmB(GB, 1);  // NC=256 / NC=128

    hipMemsetAsync(d_ws, 0, zbytes, stream);
    count_k<<<(NE + 255) / 256, 256, 0, stream>>>(ei, batch, degcnt, gcnt);
    scan1_k<<<SCB, 256, 0, stream>>>(degcnt, part);
    scan2_k<<<1, 64, 0, stream>>>(part, rowptr);
    scan3_k<<<SCB, 256, 0, stream>>>(degcnt, part, rowptr, fillpos);
    fill_k<<<(NE + 255) / 256, 256, 0, stream>>>(ei, fillpos, esrc);
    wtrans_k<<<dim3(8, 8, 8), 256, 0, stream>>>(wp);
    vinit_k<<<(NG * DH + 255) / 256, 256, 0, stream>>>(vn_emb, vfeat);

    // ---- layer 1 ----
    agg_k<<<NN / 4, 256, 0, stream>>>(x, rowptr, esrc, hb);
    mgemm_k<128, 256><<<gemmA, 256, 0, stream>>>(hb, Wt[0], c1_b1, b1, sA[0], qA[0], NN);
    bnrelu_k<256><<<2048, 256, 0, stream>>>(b1, b1, sA[0], qA[0], c1_bng, c1_bnb,
                                            nullptr, nullptr, NN, 1);
    mgemm_k<256, 128><<<gemmB, 256, 0, stream>>>(b1, Wt[1], c1_b2, abuf, sB[0], qB[0], NN);
    // bn1 + relu + fused vn-add (layer2 input = relu(bn(...)) + vfeat0[batch])
    bnrelu_k<128><<<2048, 256, 0, stream>>>(abuf, abuf, sB[0], qB[0], bn1_g, bn1_b,
                                            vfeat, batch, NN, 1);

    // ---- layer 2 ----
    agg_k<<<NN / 4, 256, 0, stream>>>(abuf, rowptr, esrc, hb);
    mgemm_k<128, 256><<<gemmA, 256, 0, stream>>>(hb, Wt[2], cb1, b1, sA[1], qA[1], NN);
    bnrelu_k<256><<<2048, 256, 0, stream>>>(b1, b1, sA[1], qA[1], cbng, cbnb,
                                            nullptr, nullptr, NN, 1);
    mgemm_k<256, 128><<<gemmB, 256, 0, stream>>>(b1, Wt[3], cb2, abuf, sB[1], qB[1], NN);
    bnpool_k<<<GB, 256, 0, stream>>>(abuf, abuf, sB[1], qB[1], bns_g, bns_b,
                                     batch, pooled, NN, 1);

    // ---- virtual-node MLP (M = 512) ----
    zin_k<<<(NG * DH + 255) / 256, 256, 0, stream>>>(pooled, vfeat, zin);
    mgemm_k<128, 256><<<dim3(4, 2), 256, 0, stream>>>(zin, Wt[6], vb1, zb, sV1, qV1, NG);
    bnrelu_k<256><<<64, 256, 0, stream>>>(zb, zb, sV1, qV1, vbn1_g, vbn1_b,
                                          nullptr, nullptr, NG, 1);
    mgemm_k<256, 128><<<dim3(4, 1), 256, 0, stream>>>(zb, Wt[7], vb2, vraw, sV2, qV2, NG);
    bnrelu_k<128><<<32, 256, 0, stream>>>(vraw, vfeat, sV2, qV2, vbn2_g, vbn2_b,
                                          nullptr, nullptr, NG, 1);

    // ---- layer 3 ----
    addvn_k<<<(NN * 32 + 255) / 256, 256, 0, stream>>>(abuf, vfeat, batch);
    agg_k<<<NN / 4, 256, 0, stream>>>(abuf, rowptr, esrc, hb);
    mgemm_k<128, 256><<<gemmA, 256, 0, stream>>>(hb, Wt[4], cb1 + 256, b1, sA[2], qA[2], NN);
    bnrelu_k<256><<<2048, 256, 0, stream>>>(b1, b1, sA[2], qA[2], cbng + 256, cbnb + 256,
                                            nullptr, nullptr, NN, 1);
    mgemm_k<256, 128><<<gemmB, 256, 0, stream>>>(b1, Wt[5], cb2 + 128, abuf, sB[2], qB[2], NN);
    bnpool_k<<<GB, 256, 0, stream>>>(abuf, nullptr, sB[2], qB[2], bns_g + 128, bns_b + 128,
                                     batch, pooled2, NN, 0);

    finalout_k<<<(NG * DH + 255) / 256, 256, 0, stream>>>(pooled2, gcnt, outp);
}

// Round 5
// 1235.225 us; speedup vs baseline: 2.2956x; 1.1673x over previous
//
#include <hip/hip_runtime.h>

#define NN 100000
#define NE 1600000
#define NG 512
#define DH 128
#define DH2 256
#define SCB 98  // ceil(NN / 1024)

typedef __attribute__((ext_vector_type(8))) _Float16 h8;  // 8 f16 (4 VGPRs)
typedef __attribute__((ext_vector_type(4))) float f4;     // MFMA C/D frag

static inline size_t align256(size_t x) { return (x + 255) & ~size_t(255); }

// ---- CSR build: slot trick (one atomic pass instead of two) -------------
// pass A: slot[e] = rank of edge e among edges sharing its dst; cursor -> deg
__global__ __launch_bounds__(256) void countslot_k(const int* __restrict__ ei,
                                                   int* __restrict__ cursor,
                                                   int* __restrict__ slot) {
    int i = blockIdx.x * blockDim.x + threadIdx.x;
    int stride = gridDim.x * blockDim.x;
    for (int e = i; e < NE; e += stride)
        slot[e] = atomicAdd(&cursor[ei[NE + e]], 1);
}

// pass B: plain scattered stores (cached), no atomics
__global__ __launch_bounds__(256) void place_k(const int* __restrict__ ei,
                                               const int* __restrict__ rowptr,
                                               const int* __restrict__ slot,
                                               int* __restrict__ esrc) {
    int i = blockIdx.x * blockDim.x + threadIdx.x;
    int stride = gridDim.x * blockDim.x;
    for (int e = i; e < NE; e += stride)
        esrc[rowptr[ei[NE + e]] + slot[e]] = ei[e];
}

// per-graph node counts via binary search over sorted batch (no atomics)
__global__ void gbound_k(const int* __restrict__ batch, int* __restrict__ gcnt) {
    int g = blockIdx.x * blockDim.x + threadIdx.x;
    if (g >= NG) return;
    int lo = 0, hi = NN;
    while (lo < hi) { int m = (lo + hi) >> 1; if (batch[m] < g) lo = m + 1; else hi = m; }
    int b0 = lo;
    lo = 0; hi = NN;
    int g1 = g + 1;
    while (lo < hi) { int m = (lo + hi) >> 1; if (batch[m] < g1) lo = m + 1; else hi = m; }
    gcnt[g] = lo - b0;
}

// 3-kernel device-wide exclusive scan of deg[NN] -> rowptr
__global__ __launch_bounds__(256) void scan1_k(const int* __restrict__ deg,
                                               int* __restrict__ part) {
    int i0 = blockIdx.x * 1024 + threadIdx.x * 4;
    int s = 0;
    if (i0 < NN) {  // NN % 4 == 0, int4 fully in-range
        int4 v = *(const int4*)(deg + i0);
        s = v.x + v.y + v.z + v.w;
    }
#pragma unroll
    for (int o = 1; o < 64; o <<= 1) s += __shfl_xor(s, o);
    __shared__ int ws[4];
    if ((threadIdx.x & 63) == 0) ws[threadIdx.x >> 6] = s;
    __syncthreads();
    if (threadIdx.x == 0) part[blockIdx.x] = ws[0] + ws[1] + ws[2] + ws[3];
}

__global__ void scan2_k(int* __restrict__ part, int* __restrict__ rowptr) {
    if (threadIdx.x == 0) {
        int run = 0;
        for (int i = 0; i < SCB; i++) { int v = part[i]; part[i] = run; run += v; }
        rowptr[NN] = run;
    }
}

__global__ __launch_bounds__(256) void scan3_k(const int* __restrict__ deg,
                                               const int* __restrict__ part,
                                               int* __restrict__ rowptr) {
    int t = threadIdx.x;
    int i0 = blockIdx.x * 1024 + t * 4;
    int4 v = {0, 0, 0, 0};
    if (i0 < NN) v = *(const int4*)(deg + i0);
    int s = v.x + v.y + v.z + v.w;
    __shared__ int sc[256];
    sc[t] = s;
    __syncthreads();
    for (int o = 1; o < 256; o <<= 1) {
        int add = (t >= o) ? sc[t - o] : 0;
        __syncthreads();
        sc[t] += add;
        __syncthreads();
    }
    int excl = (t ? sc[t - 1] : 0) + part[blockIdx.x];
    if (i0 < NN) {
        int4 r;
        r.x = excl;
        r.y = excl + v.x;
        r.z = excl + v.x + v.y;
        r.w = excl + v.x + v.y + v.z;
        *(int4*)(rowptr + i0) = r;
    }
}

// ---- small ops ----------------------------------------------------------
__global__ void vinit_k(const float* __restrict__ emb, float* __restrict__ vfeat) {
    int i = blockIdx.x * blockDim.x + threadIdx.x;  // NG*DH
    if (i < NG * DH) vfeat[i] = emb[i & (DH - 1)];
}

__global__ void zin_k(const float* __restrict__ pooled, const float* __restrict__ vf,
                      float* __restrict__ zb) {
    int i = blockIdx.x * blockDim.x + threadIdx.x;  // NG*DH
    if (i < NG * DH) zb[i] = pooled[i] + vf[i];
}

__global__ void addvn_k(float* __restrict__ x, const float* __restrict__ vfeat,
                        const int* __restrict__ batch) {
    int i = blockIdx.x * blockDim.x + threadIdx.x;  // NN*32 float4s
    if (i >= NN * 32) return;
    int row = i >> 5;
    int bg = batch[row];
    float4 u = ((float4*)x)[i];
    float4 v = ((const float4*)vfeat)[bg * 32 + (i & 31)];
    u.x += v.x; u.y += v.y; u.z += v.z; u.w += v.w;
    ((float4*)x)[i] = u;
}

__global__ void finalout_k(const float* __restrict__ pooled2, const int* __restrict__ gcnt,
                           float* __restrict__ outp) {
    int i = blockIdx.x * blockDim.x + threadIdx.x;
    if (i >= NG * DH) return;
    float cnt = (float)gcnt[i >> 7];
    outp[i] = pooled2[i] / fmaxf(cnt, 1.0f);
}

// ---- weight transpose+cast: W[K][N] f32 -> Wt[N][K] f16 -----------------
struct WPack {
    const float* w[8];
    _Float16* wt[8];
    int K[8];
    int N[8];
};
__global__ void wtrans_k(WPack p) {
    int id = blockIdx.z;
    const float* W = p.w[id];
    _Float16* Wt = p.wt[id];
    int K = p.K[id], N = p.N[id];
    int n0 = blockIdx.x * 32, k0 = blockIdx.y * 32;
    if (n0 >= N || k0 >= K) return;
    __shared__ float t[32][33];
    int tx = threadIdx.x & 31, ty = threadIdx.x >> 5;  // 256 thr: 8 rows
    for (int i = 0; i < 32; i += 8)
        t[ty + i][tx] = W[(size_t)(k0 + ty + i) * N + n0 + tx];
    __syncthreads();
    for (int i = 0; i < 32; i += 8)
        Wt[(size_t)(n0 + ty + i) * K + k0 + tx] = (_Float16)t[tx][ty + i];
}

// ---- aggregation: out[n] = in[n] + sum_j in[src_j]  (f32, wave/node) ----
__global__ __launch_bounds__(256) void agg_k(const float* __restrict__ xin,
                                             const int* __restrict__ rowptr,
                                             const int* __restrict__ esrc,
                                             float* __restrict__ out) {
    int wave = threadIdx.x >> 6, lane = threadIdx.x & 63;
    int node = blockIdx.x * 4 + wave;
    if (node >= NN) return;
    const float2* xr = (const float2*)xin;
    float2 self = xr[(size_t)node * 64 + lane];
    float a0 = self.x, a1 = self.y;
    int beg = rowptr[node], end = rowptr[node + 1];
    int j = beg;
    for (; j + 3 < end; j += 4) {
        int s0 = esrc[j], s1 = esrc[j + 1], s2 = esrc[j + 2], s3 = esrc[j + 3];
        float2 u0 = xr[(size_t)s0 * 64 + lane];
        float2 u1 = xr[(size_t)s1 * 64 + lane];
        float2 u2 = xr[(size_t)s2 * 64 + lane];
        float2 u3 = xr[(size_t)s3 * 64 + lane];
        a0 += u0.x + u1.x + u2.x + u3.x;
        a1 += u0.y + u1.y + u2.y + u3.y;
    }
    for (; j < end; j++) {
        float2 u = xr[(size_t)esrc[j] * 64 + lane];
        a0 += u.x; a1 += u.y;
    }
    float2 o; o.x = a0; o.y = a1;
    ((float2*)out)[(size_t)node * 64 + lane] = o;
}

// ---- MFMA GEMM: C[M x NCF] = A[M x K] @ W + bias, col sum/sumsq fused ---
// A row-major f32 (cast to f16 during LDS staging); Wt[NCF][K] f16.
// Optional fused BN+ReLU applied to A during staging (bnsum != nullptr):
// exact same f32 math as the standalone bnrelu pass it replaces.
// block tile 128x128, 4 waves 2x2, wave tile 64x64 = 4x4 frags of 16x16x32.
template <int K, int NCF>
__global__ __launch_bounds__(256, 2) void mgemm_k(
        const float* __restrict__ A, const _Float16* __restrict__ Wt,
        const float* __restrict__ bias, float* __restrict__ C,
        float* __restrict__ csum, float* __restrict__ csq, int M,
        const float* __restrict__ bnsum, const float* __restrict__ bnsq,
        const float* __restrict__ bng, const float* __restrict__ bnb) {
    constexpr int BK = 128;
    constexpr int LDA = BK + 8;  // +16B pad: frag reads spread across bank groups
    __shared__ __align__(16) _Float16 As[128 * LDA];
    const int tid = threadIdx.x;
    const int lane = tid & 63;
    const int wave = tid >> 6;
    const int wr = wave & 1, wc = wave >> 1;
    const int lm = lane & 15, lq = lane >> 4;
    const int mB = blockIdx.x * 128;
    const int n0 = blockIdx.y * 128 + wc * 64;

    f4 acc[4][4];
#pragma unroll
    for (int i = 0; i < 4; i++)
#pragma unroll
        for (int j = 0; j < 4; j++) acc[i][j] = (f4){0.f, 0.f, 0.f, 0.f};

    const int sr = tid >> 4;         // staging row within 16-row group
    const int sc = (tid & 15) * 8;   // staging elem offset (8 elems = 2 float4)

    for (int kc = 0; kc < K; kc += BK) {
        if (kc) __syncthreads();
        float bscv[8], bshv[8];
        if (bnsum) {
            float invM = 1.0f / (float)M;
#pragma unroll
            for (int e = 0; e < 8; e++) {
                int col = kc + sc + e;
                float mean = bnsum[col] * invM;
                float var = bnsq[col] * invM - mean * mean;
                bscv[e] = bng[col] * rsqrtf(var + 1e-5f);
                bshv[e] = bnb[col] - mean * bscv[e];
            }
        }
#pragma unroll
        for (int rr = 0; rr < 128; rr += 16) {
            int gr = mB + rr + sr; if (gr >= M) gr = M - 1;
            const float* src = A + (size_t)gr * K + kc + sc;
            float4 p = *(const float4*)src;
            float4 q = *(const float4*)(src + 4);
            if (bnsum) {
                p.x = fmaxf(p.x * bscv[0] + bshv[0], 0.f);
                p.y = fmaxf(p.y * bscv[1] + bshv[1], 0.f);
                p.z = fmaxf(p.z * bscv[2] + bshv[2], 0.f);
                p.w = fmaxf(p.w * bscv[3] + bshv[3], 0.f);
                q.x = fmaxf(q.x * bscv[4] + bshv[4], 0.f);
                q.y = fmaxf(q.y * bscv[5] + bshv[5], 0.f);
                q.z = fmaxf(q.z * bscv[6] + bshv[6], 0.f);
                q.w = fmaxf(q.w * bscv[7] + bshv[7], 0.f);
            }
            h8 h = {(_Float16)p.x, (_Float16)p.y, (_Float16)p.z, (_Float16)p.w,
                    (_Float16)q.x, (_Float16)q.y, (_Float16)q.z, (_Float16)q.w};
            *(h8*)&As[(rr + sr) * LDA + sc] = h;
        }
        __syncthreads();
#pragma unroll
        for (int ks = 0; ks < BK / 32; ks++) {
            h8 af[4], bf[4];
#pragma unroll
            for (int t = 0; t < 4; t++) {
                af[t] = *(const h8*)&As[(wr * 64 + t * 16 + lm) * LDA + ks * 32 + lq * 8];
                bf[t] = *(const h8*)&Wt[(size_t)(n0 + t * 16 + lm) * K + kc + ks * 32 + lq * 8];
            }
#pragma unroll
            for (int i = 0; i < 4; i++)
#pragma unroll
                for (int j = 0; j < 4; j++)
                    acc[i][j] = __builtin_amdgcn_mfma_f32_16x16x32_f16(af[i], bf[j], acc[i][j], 0, 0, 0);
        }
    }

    // epilogue: bias, store f32, column stats
    float bv[4];
#pragma unroll
    for (int j = 0; j < 4; j++) bv[j] = bias[n0 + j * 16 + lm];
    float ls[4] = {0, 0, 0, 0}, lsq[4] = {0, 0, 0, 0};
    const int m0 = mB + wr * 64;
#pragma unroll
    for (int i = 0; i < 4; i++) {
#pragma unroll
        for (int j = 0; j < 4; j++) {
#pragma unroll
            for (int r = 0; r < 4; r++) {
                int row = m0 + i * 16 + lq * 4 + r;
                if (row < M) {
                    float v = acc[i][j][r] + bv[j];
                    C[(size_t)row * NCF + n0 + j * 16 + lm] = v;
                    ls[j] += v; lsq[j] += v * v;
                }
            }
        }
    }
#pragma unroll
    for (int j = 0; j < 4; j++) {
        float s = ls[j], q = lsq[j];
        s += __shfl_xor(s, 16); s += __shfl_xor(s, 32);
        q += __shfl_xor(q, 16); q += __shfl_xor(q, 32);
        if (lq == 0) {
            atomicAdd(&csum[n0 + j * 16 + lm], s);
            atomicAdd(&csq[n0 + j * 16 + lm], q);
        }
    }
}

// ---- BN apply (+relu, +optional vn-add after relu), f32 x4 vectorized ---
template <int NC>
__global__ void bnrelu_k(const float* __restrict__ in, float* __restrict__ out,
                         const float* __restrict__ csum, const float* __restrict__ csq,
                         const float* __restrict__ g, const float* __restrict__ b,
                         const float* __restrict__ vfeat, const int* __restrict__ batch,
                         int M, int relu) {
    constexpr int PER = NC / 4;  // float4s per row
    int tid = blockIdx.x * blockDim.x + threadIdx.x;
    int c4 = tid % PER;          // stride is a multiple of PER -> col fixed
    int c0 = c4 * 4;
    float invM = 1.0f / (float)M;
    float sc[4], sh[4];
#pragma unroll
    for (int e = 0; e < 4; e++) {
        int col = c0 + e;
        float mean = csum[col] * invM;
        float var = csq[col] * invM - mean * mean;
        sc[e] = g[col] * rsqrtf(var + 1e-5f);
        sh[e] = b[col] - mean * sc[e];
    }
    int total = M * PER;
    int stride = gridDim.x * blockDim.x;
    for (int i = tid; i < total; i += stride) {
        int row = i / PER;
        float4 u = ((const float4*)in)[i];
        float v[4] = {u.x, u.y, u.z, u.w};
        float4 w = {0.f, 0.f, 0.f, 0.f};
        if (vfeat) w = ((const float4*)vfeat)[batch[row] * PER + c4];
#pragma unroll
        for (int e = 0; e < 4; e++) {
            float vv = v[e] * sc[e] + sh[e];
            if (relu) vv = fmaxf(vv, 0.f);
            v[e] = vv;
        }
        float4 o; o.x = v[0] + w.x; o.y = v[1] + w.y; o.z = v[2] + w.z; o.w = v[3] + w.w;
        ((float4*)out)[i] = o;
    }
}

// ---- BN apply + segment-sum pool over sorted batch (NC=128, f32) --------
__global__ __launch_bounds__(256) void bnpool_k(
        const float* __restrict__ in, float* __restrict__ out,
        const float* __restrict__ csum, const float* __restrict__ csq,
        const float* __restrict__ g, const float* __restrict__ b,
        const int* __restrict__ batch, float* __restrict__ pooled,
        int M, int relu) {
    int t = threadIdx.x;
    int c0 = (t & 63) * 2;
    int r0 = blockIdx.x * 128 + (t >> 6) * 32;
    float invM = 1.0f / (float)M;
    float mean0 = csum[c0] * invM;
    float var0 = csq[c0] * invM - mean0 * mean0;
    float s0 = g[c0] * rsqrtf(var0 + 1e-5f), h0 = b[c0] - mean0 * s0;
    float mean1 = csum[c0 + 1] * invM;
    float var1 = csq[c0 + 1] * invM - mean1 * mean1;
    float s1 = g[c0 + 1] * rsqrtf(var1 + 1e-5f), h1 = b[c0 + 1] - mean1 * s1;
    int rend = r0 + 32; if (rend > M) rend = M;
    float a0 = 0.f, a1 = 0.f; int cur = -1;
    for (int r = r0; r < rend; r++) {
        float2 u = ((const float2*)in)[(size_t)r * 64 + (c0 >> 1)];
        float v0 = u.x * s0 + h0;
        float v1 = u.y * s1 + h1;
        if (relu) { v0 = fmaxf(v0, 0.f); v1 = fmaxf(v1, 0.f); }
        if (out) { float2 o; o.x = v0; o.y = v1; ((float2*)out)[(size_t)r * 64 + (c0 >> 1)] = o; }
        int bg = batch[r];
        if (bg != cur) {
            if (cur >= 0) {
                atomicAdd(&pooled[(size_t)cur * DH + c0], a0);
                atomicAdd(&pooled[(size_t)cur * DH + c0 + 1], a1);
            }
            cur = bg; a0 = 0.f; a1 = 0.f;
        }
        a0 += v0; a1 += v1;
    }
    if (cur >= 0) {
        atomicAdd(&pooled[(size_t)cur * DH + c0], a0);
        atomicAdd(&pooled[(size_t)cur * DH + c0 + 1], a1);
    }
}

// ------------------------------------------------------------------------
extern "C" void kernel_launch(void* const* d_in, const int* in_sizes, int n_in,
                              void* d_out, int out_size, void* d_ws, size_t ws_size,
                              hipStream_t stream) {
    const float* x      = (const float*)d_in[0];
    const int*   ei     = (const int*)d_in[1];
    const int*   batch  = (const int*)d_in[2];
    const float* vn_emb = (const float*)d_in[3];
    const float* c1_W1  = (const float*)d_in[4];
    const float* c1_b1  = (const float*)d_in[5];
    const float* c1_bng = (const float*)d_in[6];
    const float* c1_bnb = (const float*)d_in[7];
    const float* c1_W2  = (const float*)d_in[8];
    const float* c1_b2  = (const float*)d_in[9];
    const float* bn1_g  = (const float*)d_in[10];
    const float* bn1_b  = (const float*)d_in[11];
    const float* cW1    = (const float*)d_in[12];
    const float* cb1    = (const float*)d_in[13];
    const float* cbng   = (const float*)d_in[14];
    const float* cbnb   = (const float*)d_in[15];
    const float* cW2    = (const float*)d_in[16];
    const float* cb2    = (const float*)d_in[17];
    const float* bns_g  = (const float*)d_in[18];
    const float* bns_b  = (const float*)d_in[19];
    const float* vW1    = (const float*)d_in[20];
    const float* vb1    = (const float*)d_in[21];
    const float* vbn1_g = (const float*)d_in[22];
    const float* vbn1_b = (const float*)d_in[23];
    const float* vW2    = (const float*)d_in[24];
    const float* vb2    = (const float*)d_in[25];
    const float* vbn2_g = (const float*)d_in[26];
    const float* vbn2_b = (const float*)d_in[27];
    float* outp = (float*)d_out;
    (void)in_sizes; (void)n_in; (void)out_size; (void)ws_size;

    char* w = (char*)d_ws;
    size_t off = 0;
    auto carve = [&](size_t bytes) -> void* {
        void* p = w + off; off = align256(off + bytes); return p;
    };
    // zero-init region
    int*   cursor  = (int*)carve((size_t)NN * 4);
    float* pooled  = (float*)carve((size_t)NG * DH * 4);
    float* pooled2 = (float*)carve((size_t)NG * DH * 4);
    float* stats   = (float*)carve(3072 * 4);
    size_t zbytes = off;
    float *sA[3], *qA[3], *sB[3], *qB[3];
    float* sp = stats;
    for (int i = 0; i < 3; i++) { sA[i] = sp; sp += 256; qA[i] = sp; sp += 256; }
    for (int i = 0; i < 3; i++) { sB[i] = sp; sp += 128; qB[i] = sp; sp += 128; }
    float* sV1 = sp; sp += 256; float* qV1 = sp; sp += 256;
    float* sV2 = sp; sp += 128; float* qV2 = sp; sp += 128;
    // non-zeroed region
    int*   gcnt    = (int*)carve((size_t)NG * 4);
    int*   rowptr  = (int*)carve((size_t)(NN + 1) * 4);
    int*   slot    = (int*)carve((size_t)NE * 4);
    int*   esrc    = (int*)carve((size_t)NE * 4);
    int*   part    = (int*)carve((size_t)SCB * 4);
    float* vfeat   = (float*)carve((size_t)NG * DH * 4);
    float* zin     = (float*)carve((size_t)NG * DH * 4);
    float* zb      = (float*)carve((size_t)NG * DH2 * 4);
    float* vraw    = (float*)carve((size_t)NG * DH * 4);
    float* hb      = (float*)carve((size_t)NN * DH * 4);
    float* b1      = (float*)carve((size_t)NN * DH2 * 4);
    float* abuf    = (float*)carve((size_t)NN * DH * 4);
    _Float16* Wt[8];
    // shapes: [0]=c1_W1 128x256, [1]=c1_W2 256x128, [2]=cW1_0, [3]=cW2_0,
    //         [4]=cW1_1, [5]=cW2_1, [6]=vW1, [7]=vW2
    for (int i = 0; i < 8; i++) Wt[i] = (_Float16*)carve((size_t)DH * DH2 * 2);

    WPack wp;
    wp.w[0] = c1_W1;            wp.K[0] = 128; wp.N[0] = 256;
    wp.w[1] = c1_W2;            wp.K[1] = 256; wp.N[1] = 128;
    wp.w[2] = cW1;              wp.K[2] = 128; wp.N[2] = 256;
    wp.w[3] = cW2;              wp.K[3] = 256; wp.N[3] = 128;
    wp.w[4] = cW1 + 128 * 256;  wp.K[4] = 128; wp.N[4] = 256;
    wp.w[5] = cW2 + 256 * 128;  wp.K[5] = 256; wp.N[5] = 128;
    wp.w[6] = vW1;              wp.K[6] = 128; wp.N[6] = 256;
    wp.w[7] = vW2;              wp.K[7] = 256; wp.N[7] = 128;
    for (int i = 0; i < 8; i++) wp.wt[i] = Wt[i];

    const int GB = (NN + 127) / 128;  // 782
    dim3 gemmA(GB, 2), gemmB(GB, 1);  // NC=256 / NC=128
    const float* NUL = nullptr;

    hipMemsetAsync(d_ws, 0, zbytes, stream);
    countslot_k<<<782, 256, 0, stream>>>(ei, cursor, slot);
    scan1_k<<<SCB, 256, 0, stream>>>(cursor, part);
    scan2_k<<<1, 64, 0, stream>>>(part, rowptr);
    scan3_k<<<SCB, 256, 0, stream>>>(cursor, part, rowptr);
    place_k<<<782, 256, 0, stream>>>(ei, rowptr, slot, esrc);
    gbound_k<<<2, 256, 0, stream>>>(batch, gcnt);
    wtrans_k<<<dim3(8, 8, 8), 256, 0, stream>>>(wp);
    vinit_k<<<(NG * DH + 255) / 256, 256, 0, stream>>>(vn_emb, vfeat);

    // ---- layer 1 ----
    agg_k<<<NN / 4, 256, 0, stream>>>(x, rowptr, esrc, hb);
    mgemm_k<128, 256><<<gemmA, 256, 0, stream>>>(hb, Wt[0], c1_b1, b1, sA[0], qA[0], NN,
                                                 NUL, NUL, NUL, NUL);
    mgemm_k<256, 128><<<gemmB, 256, 0, stream>>>(b1, Wt[1], c1_b2, abuf, sB[0], qB[0], NN,
                                                 sA[0], qA[0], c1_bng, c1_bnb);
    // bn1 + relu + fused vn-add (layer2 input = relu(bn(...)) + vfeat0[batch])
    bnrelu_k<128><<<2048, 256, 0, stream>>>(abuf, abuf, sB[0], qB[0], bn1_g, bn1_b,
                                            vfeat, batch, NN, 1);

    // ---- layer 2 ----
    agg_k<<<NN / 4, 256, 0, stream>>>(abuf, rowptr, esrc, hb);
    mgemm_k<128, 256><<<gemmA, 256, 0, stream>>>(hb, Wt[2], cb1, b1, sA[1], qA[1], NN,
                                                 NUL, NUL, NUL, NUL);
    mgemm_k<256, 128><<<gemmB, 256, 0, stream>>>(b1, Wt[3], cb2, abuf, sB[1], qB[1], NN,
                                                 sA[1], qA[1], cbng, cbnb);
    bnpool_k<<<GB, 256, 0, stream>>>(abuf, abuf, sB[1], qB[1], bns_g, bns_b,
                                     batch, pooled, NN, 1);

    // ---- virtual-node MLP (M = 512) ----
    zin_k<<<(NG * DH + 255) / 256, 256, 0, stream>>>(pooled, vfeat, zin);
    mgemm_k<128, 256><<<dim3(4, 2), 256, 0, stream>>>(zin, Wt[6], vb1, zb, sV1, qV1, NG,
                                                      NUL, NUL, NUL, NUL);
    mgemm_k<256, 128><<<dim3(4, 1), 256, 0, stream>>>(zb, Wt[7], vb2, vraw, sV2, qV2, NG,
                                                      sV1, qV1, vbn1_g, vbn1_b);
    bnrelu_k<128><<<32, 256, 0, stream>>>(vraw, vfeat, sV2, qV2, vbn2_g, vbn2_b,
                                          nullptr, nullptr, NG, 1);

    // ---- layer 3 ----
    addvn_k<<<(NN * 32 + 255) / 256, 256, 0, stream>>>(abuf, vfeat, batch);
    agg_k<<<NN / 4, 256, 0, stream>>>(abuf, rowptr, esrc, hb);
    mgemm_k<128, 256><<<gemmA, 256, 0, stream>>>(hb, Wt[4], cb1 + 256, b1, sA[2], qA[2], NN,
                                                 NUL, NUL, NUL, NUL);
    mgemm_k<256, 128><<<gemmB, 256, 0, stream>>>(b1, Wt[5], cb2 + 128, abuf, sB[2], qB[2], NN,
                                                 sA[2], qA[2], cbng + 256, cbnb + 256);
    bnpool_k<<<GB, 256, 0, stream>>>(abuf, nullptr, sB[2], qB[2], bns_g + 128, bns_b + 128,
                                     batch, pooled2, NN, 0);

    finalout_k<<<(NG * DH + 255) / 256, 256, 0, stream>>>(pooled2, gcnt, outp);
}

// Round 6
// 1075.274 us; speedup vs baseline: 2.6371x; 1.1488x over previous
//
#include <hip/hip_runtime.h>

#define NN 100000
#define NE 1600000
#define NG 512
#define DH 128
#define DH2 256
#define SCB 98  // ceil(NN / 1024)

typedef __attribute__((ext_vector_type(8))) _Float16 h8;  // 8 f16 (4 VGPRs)
typedef __attribute__((ext_vector_type(2))) _Float16 h2;
typedef __attribute__((ext_vector_type(4))) float f4;     // MFMA C/D frag

static inline size_t align256(size_t x) { return (x + 255) & ~size_t(255); }

// ---- CSR build: slot trick (one atomic pass instead of two) -------------
__global__ __launch_bounds__(256) void countslot_k(const int* __restrict__ ei,
                                                   int* __restrict__ cursor,
                                                   int* __restrict__ slot) {
    int i = blockIdx.x * blockDim.x + threadIdx.x;
    int stride = gridDim.x * blockDim.x;
    for (int e = i; e < NE; e += stride)
        slot[e] = atomicAdd(&cursor[ei[NE + e]], 1);
}

__global__ __launch_bounds__(256) void place_k(const int* __restrict__ ei,
                                               const int* __restrict__ rowptr,
                                               const int* __restrict__ slot,
                                               int* __restrict__ esrc) {
    int i = blockIdx.x * blockDim.x + threadIdx.x;
    int stride = gridDim.x * blockDim.x;
    for (int e = i; e < NE; e += stride)
        esrc[rowptr[ei[NE + e]] + slot[e]] = ei[e];
}

__global__ void gbound_k(const int* __restrict__ batch, int* __restrict__ gcnt) {
    int g = blockIdx.x * blockDim.x + threadIdx.x;
    if (g >= NG) return;
    int lo = 0, hi = NN;
    while (lo < hi) { int m = (lo + hi) >> 1; if (batch[m] < g) lo = m + 1; else hi = m; }
    int b0 = lo;
    lo = 0; hi = NN;
    int g1 = g + 1;
    while (lo < hi) { int m = (lo + hi) >> 1; if (batch[m] < g1) lo = m + 1; else hi = m; }
    gcnt[g] = lo - b0;
}

// 3-kernel device-wide exclusive scan of deg[NN] -> rowptr
__global__ __launch_bounds__(256) void scan1_k(const int* __restrict__ deg,
                                               int* __restrict__ part) {
    int i0 = blockIdx.x * 1024 + threadIdx.x * 4;
    int s = 0;
    if (i0 < NN) {
        int4 v = *(const int4*)(deg + i0);
        s = v.x + v.y + v.z + v.w;
    }
#pragma unroll
    for (int o = 1; o < 64; o <<= 1) s += __shfl_xor(s, o);
    __shared__ int ws[4];
    if ((threadIdx.x & 63) == 0) ws[threadIdx.x >> 6] = s;
    __syncthreads();
    if (threadIdx.x == 0) part[blockIdx.x] = ws[0] + ws[1] + ws[2] + ws[3];
}

__global__ void scan2_k(int* __restrict__ part, int* __restrict__ rowptr) {
    if (threadIdx.x == 0) {
        int run = 0;
        for (int i = 0; i < SCB; i++) { int v = part[i]; part[i] = run; run += v; }
        rowptr[NN] = run;
    }
}

__global__ __launch_bounds__(256) void scan3_k(const int* __restrict__ deg,
                                               const int* __restrict__ part,
                                               int* __restrict__ rowptr) {
    int t = threadIdx.x;
    int i0 = blockIdx.x * 1024 + t * 4;
    int4 v = {0, 0, 0, 0};
    if (i0 < NN) v = *(const int4*)(deg + i0);
    int s = v.x + v.y + v.z + v.w;
    __shared__ int sc[256];
    sc[t] = s;
    __syncthreads();
    for (int o = 1; o < 256; o <<= 1) {
        int add = (t >= o) ? sc[t - o] : 0;
        __syncthreads();
        sc[t] += add;
        __syncthreads();
    }
    int excl = (t ? sc[t - 1] : 0) + part[blockIdx.x];
    if (i0 < NN) {
        int4 r;
        r.x = excl;
        r.y = excl + v.x;
        r.z = excl + v.x + v.y;
        r.w = excl + v.x + v.y + v.z;
        *(int4*)(rowptr + i0) = r;
    }
}

// ---- small ops ----------------------------------------------------------
__global__ void castx_k(const float* __restrict__ x, _Float16* __restrict__ xh) {
    int i = blockIdx.x * blockDim.x + threadIdx.x;  // NN*16 h8 chunks
    if (i >= NN * 16) return;
    const float4* s = (const float4*)x + i * 2;
    float4 p = s[0], q = s[1];
    h8 h = {(_Float16)p.x, (_Float16)p.y, (_Float16)p.z, (_Float16)p.w,
            (_Float16)q.x, (_Float16)q.y, (_Float16)q.z, (_Float16)q.w};
    ((h8*)xh)[i] = h;
}

__global__ void vinit_k(const float* __restrict__ emb, _Float16* __restrict__ vfeat) {
    int i = blockIdx.x * blockDim.x + threadIdx.x;  // NG*DH
    if (i < NG * DH) vfeat[i] = (_Float16)emb[i & (DH - 1)];
}

__global__ void zin_k(const float* __restrict__ pooled, const _Float16* __restrict__ vf,
                      _Float16* __restrict__ zb) {
    int i = blockIdx.x * blockDim.x + threadIdx.x;  // NG*DH
    if (i < NG * DH) zb[i] = (_Float16)(pooled[i] + (float)vf[i]);
}

__global__ void addvn_k(_Float16* __restrict__ x, const _Float16* __restrict__ vfeat,
                        const int* __restrict__ batch) {
    int i = blockIdx.x * blockDim.x + threadIdx.x;  // NN*16 h8 chunks
    if (i >= NN * 16) return;
    int row = i >> 4;
    int bg = batch[row];
    h8 u = ((h8*)x)[i];
    h8 v = ((const h8*)vfeat)[bg * 16 + (i & 15)];
    h8 o;
#pragma unroll
    for (int e = 0; e < 8; e++) o[e] = (_Float16)((float)u[e] + (float)v[e]);
    ((h8*)x)[i] = o;
}

__global__ void finalout_k(const float* __restrict__ pooled2, const int* __restrict__ gcnt,
                           float* __restrict__ outp) {
    int i = blockIdx.x * blockDim.x + threadIdx.x;
    if (i >= NG * DH) return;
    float cnt = (float)gcnt[i >> 7];
    outp[i] = pooled2[i] / fmaxf(cnt, 1.0f);
}

// ---- weight transpose+cast: W[K][N] f32 -> Wt[N][K] f16 -----------------
struct WPack {
    const float* w[8];
    _Float16* wt[8];
    int K[8];
    int N[8];
};
__global__ void wtrans_k(WPack p) {
    int id = blockIdx.z;
    const float* W = p.w[id];
    _Float16* Wt = p.wt[id];
    int K = p.K[id], N = p.N[id];
    int n0 = blockIdx.x * 32, k0 = blockIdx.y * 32;
    if (n0 >= N || k0 >= K) return;
    __shared__ float t[32][33];
    int tx = threadIdx.x & 31, ty = threadIdx.x >> 5;
    for (int i = 0; i < 32; i += 8)
        t[ty + i][tx] = W[(size_t)(k0 + ty + i) * N + n0 + tx];
    __syncthreads();
    for (int i = 0; i < 32; i += 8)
        Wt[(size_t)(n0 + ty + i) * K + k0 + tx] = (_Float16)t[tx][ty + i];
}

// ---- aggregation: out[n] = in[n] + sum_j in[src_j]  (f16 rows, f32 acc) -
__global__ __launch_bounds__(256) void agg_k(const _Float16* __restrict__ xin,
                                             const int* __restrict__ rowptr,
                                             const int* __restrict__ esrc,
                                             _Float16* __restrict__ out) {
    int wave = threadIdx.x >> 6, lane = threadIdx.x & 63;
    int node = blockIdx.x * 4 + wave;
    if (node >= NN) return;
    const h2* xr = (const h2*)xin;
    h2 self = xr[(size_t)node * 64 + lane];
    float a0 = (float)self.x, a1 = (float)self.y;
    int beg = rowptr[node], end = rowptr[node + 1];
    int j = beg;
    for (; j + 3 < end; j += 4) {
        int s0 = esrc[j], s1 = esrc[j + 1], s2 = esrc[j + 2], s3 = esrc[j + 3];
        h2 u0 = xr[(size_t)s0 * 64 + lane];
        h2 u1 = xr[(size_t)s1 * 64 + lane];
        h2 u2 = xr[(size_t)s2 * 64 + lane];
        h2 u3 = xr[(size_t)s3 * 64 + lane];
        a0 += (float)u0.x + (float)u1.x + (float)u2.x + (float)u3.x;
        a1 += (float)u0.y + (float)u1.y + (float)u2.y + (float)u3.y;
    }
    for (; j < end; j++) {
        h2 u = xr[(size_t)esrc[j] * 64 + lane];
        a0 += (float)u.x; a1 += (float)u.y;
    }
    h2 o; o.x = (_Float16)a0; o.y = (_Float16)a1;
    ((h2*)out)[(size_t)node * 64 + lane] = o;
}

// ---- MFMA GEMM: C[M x NCF] = A[M x K] @ W + bias, col sum/sumsq fused ---
// A row-major f16; Wt[NCF][K] f16; C stored f16, stats in f32.
// Optional fused BN+ReLU applied to A during staging (bnsum != nullptr).
// block tile 128x128, 4 waves 2x2, wave tile 64x64 = 4x4 frags of 16x16x32.
template <int K, int NCF>
__global__ __launch_bounds__(256, 2) void mgemm_k(
        const _Float16* __restrict__ A, const _Float16* __restrict__ Wt,
        const float* __restrict__ bias, _Float16* __restrict__ C,
        float* __restrict__ csum, float* __restrict__ csq, int M,
        const float* __restrict__ bnsum, const float* __restrict__ bnsq,
        const float* __restrict__ bng, const float* __restrict__ bnb) {
    constexpr int BK = 128;
    constexpr int LDA = BK + 8;  // +16B pad: frag reads spread across bank groups
    __shared__ __align__(16) _Float16 As[128 * LDA];
    const int tid = threadIdx.x;
    const int lane = tid & 63;
    const int wave = tid >> 6;
    const int wr = wave & 1, wc = wave >> 1;
    const int lm = lane & 15, lq = lane >> 4;
    const int mB = blockIdx.x * 128;
    const int n0 = blockIdx.y * 128 + wc * 64;

    f4 acc[4][4];
#pragma unroll
    for (int i = 0; i < 4; i++)
#pragma unroll
        for (int j = 0; j < 4; j++) acc[i][j] = (f4){0.f, 0.f, 0.f, 0.f};

    const int sr = tid >> 4;         // staging row within 16-row group
    const int sc = (tid & 15) * 8;   // staging elem offset (8 f16 = 16 B)

    for (int kc = 0; kc < K; kc += BK) {
        if (kc) __syncthreads();
        float bscv[8], bshv[8];
        if (bnsum) {
            float invM = 1.0f / (float)M;
#pragma unroll
            for (int e = 0; e < 8; e++) {
                int col = kc + sc + e;
                float mean = bnsum[col] * invM;
                float var = bnsq[col] * invM - mean * mean;
                bscv[e] = bng[col] * rsqrtf(var + 1e-5f);
                bshv[e] = bnb[col] - mean * bscv[e];
            }
        }
#pragma unroll
        for (int rr = 0; rr < 128; rr += 16) {
            int gr = mB + rr + sr; if (gr >= M) gr = M - 1;
            h8 h = *(const h8*)&A[(size_t)gr * K + kc + sc];
            if (bnsum) {
#pragma unroll
                for (int e = 0; e < 8; e++)
                    h[e] = (_Float16)fmaxf((float)h[e] * bscv[e] + bshv[e], 0.f);
            }
            *(h8*)&As[(rr + sr) * LDA + sc] = h;
        }
        __syncthreads();
#pragma unroll
        for (int ks = 0; ks < BK / 32; ks++) {
            h8 af[4], bf[4];
#pragma unroll
            for (int t = 0; t < 4; t++) {
                af[t] = *(const h8*)&As[(wr * 64 + t * 16 + lm) * LDA + ks * 32 + lq * 8];
                bf[t] = *(const h8*)&Wt[(size_t)(n0 + t * 16 + lm) * K + kc + ks * 32 + lq * 8];
            }
#pragma unroll
            for (int i = 0; i < 4; i++)
#pragma unroll
                for (int j = 0; j < 4; j++)
                    acc[i][j] = __builtin_amdgcn_mfma_f32_16x16x32_f16(af[i], bf[j], acc[i][j], 0, 0, 0);
        }
    }

    // epilogue: bias, store f16, column stats from f32 values
    float bv[4];
#pragma unroll
    for (int j = 0; j < 4; j++) bv[j] = bias[n0 + j * 16 + lm];
    float ls[4] = {0, 0, 0, 0}, lsq[4] = {0, 0, 0, 0};
    const int m0 = mB + wr * 64;
#pragma unroll
    for (int i = 0; i < 4; i++) {
#pragma unroll
        for (int j = 0; j < 4; j++) {
#pragma unroll
            for (int r = 0; r < 4; r++) {
                int row = m0 + i * 16 + lq * 4 + r;
                if (row < M) {
                    float v = acc[i][j][r] + bv[j];
                    C[(size_t)row * NCF + n0 + j * 16 + lm] = (_Float16)v;
                    ls[j] += v; lsq[j] += v * v;
                }
            }
        }
    }
#pragma unroll
    for (int j = 0; j < 4; j++) {
        float s = ls[j], q = lsq[j];
        s += __shfl_xor(s, 16); s += __shfl_xor(s, 32);
        q += __shfl_xor(q, 16); q += __shfl_xor(q, 32);
        if (lq == 0) {
            atomicAdd(&csum[n0 + j * 16 + lm], s);
            atomicAdd(&csq[n0 + j * 16 + lm], q);
        }
    }
}

// ---- BN apply + relu (+optional vn-add after relu), f16 io, f32 math ----
// NC = 128 only.
__global__ void bnrelu_k(const _Float16* __restrict__ in, _Float16* __restrict__ out,
                         const float* __restrict__ csum, const float* __restrict__ csq,
                         const float* __restrict__ g, const float* __restrict__ b,
                         const _Float16* __restrict__ vfeat, const int* __restrict__ batch,
                         int M) {
    constexpr int PER = 16;  // h8 chunks per row
    int tid = blockIdx.x * blockDim.x + threadIdx.x;
    int c8 = tid % PER;      // grid*block stride is a multiple of PER
    int c0 = c8 * 8;
    float invM = 1.0f / (float)M;
    float sc[8], sh[8];
#pragma unroll
    for (int e = 0; e < 8; e++) {
        int col = c0 + e;
        float mean = csum[col] * invM;
        float var = csq[col] * invM - mean * mean;
        sc[e] = g[col] * rsqrtf(var + 1e-5f);
        sh[e] = b[col] - mean * sc[e];
    }
    int total = M * PER;
    int stride = gridDim.x * blockDim.x;
    for (int i = tid; i < total; i += stride) {
        int row = i / PER;
        h8 u = ((const h8*)in)[i];
        h8 w;
        bool vn = (vfeat != nullptr);
        if (vn) w = ((const h8*)vfeat)[batch[row] * PER + c8];
        h8 o;
#pragma unroll
        for (int e = 0; e < 8; e++) {
            float vv = fmaxf((float)u[e] * sc[e] + sh[e], 0.f);
            if (vn) vv += (float)w[e];
            o[e] = (_Float16)vv;
        }
        ((h8*)out)[i] = o;
    }
}

// ---- BN apply + segment-sum pool over sorted batch (NC=128) -------------
__global__ __launch_bounds__(256) void bnpool_k(
        const _Float16* __restrict__ in, _Float16* __restrict__ out,
        const float* __restrict__ csum, const float* __restrict__ csq,
        const float* __restrict__ g, const float* __restrict__ b,
        const int* __restrict__ batch, float* __restrict__ pooled,
        int M, int relu) {
    int t = threadIdx.x;
    int c0 = (t & 63) * 2;
    int r0 = blockIdx.x * 128 + (t >> 6) * 32;
    float invM = 1.0f / (float)M;
    float mean0 = csum[c0] * invM;
    float var0 = csq[c0] * invM - mean0 * mean0;
    float s0 = g[c0] * rsqrtf(var0 + 1e-5f), h0 = b[c0] - mean0 * s0;
    float mean1 = csum[c0 + 1] * invM;
    float var1 = csq[c0 + 1] * invM - mean1 * mean1;
    float s1 = g[c0 + 1] * rsqrtf(var1 + 1e-5f), h1 = b[c0 + 1] - mean1 * s1;
    int rend = r0 + 32; if (rend > M) rend = M;
    float a0 = 0.f, a1 = 0.f; int cur = -1;
    for (int r = r0; r < rend; r++) {
        h2 u = ((const h2*)in)[(size_t)r * 64 + (c0 >> 1)];
        float v0 = (float)u.x * s0 + h0;
        float v1 = (float)u.y * s1 + h1;
        if (relu) { v0 = fmaxf(v0, 0.f); v1 = fmaxf(v1, 0.f); }
        if (out) { h2 o; o.x = (_Float16)v0; o.y = (_Float16)v1; ((h2*)out)[(size_t)r * 64 + (c0 >> 1)] = o; }
        int bg = batch[r];
        if (bg != cur) {
            if (cur >= 0) {
                atomicAdd(&pooled[(size_t)cur * DH + c0], a0);
                atomicAdd(&pooled[(size_t)cur * DH + c0 + 1], a1);
            }
            cur = bg; a0 = 0.f; a1 = 0.f;
        }
        a0 += v0; a1 += v1;
    }
    if (cur >= 0) {
        atomicAdd(&pooled[(size_t)cur * DH + c0], a0);
        atomicAdd(&pooled[(size_t)cur * DH + c0 + 1], a1);
    }
}

// ------------------------------------------------------------------------
extern "C" void kernel_launch(void* const* d_in, const int* in_sizes, int n_in,
                              void* d_out, int out_size, void* d_ws, size_t ws_size,
                              hipStream_t stream) {
    const float* x      = (const float*)d_in[0];
    const int*   ei     = (const int*)d_in[1];
    const int*   batch  = (const int*)d_in[2];
    const float* vn_emb = (const float*)d_in[3];
    const float* c1_W1  = (const float*)d_in[4];
    const float* c1_b1  = (const float*)d_in[5];
    const float* c1_bng = (const float*)d_in[6];
    const float* c1_bnb = (const float*)d_in[7];
    const float* c1_W2  = (const float*)d_in[8];
    const float* c1_b2  = (const float*)d_in[9];
    const float* bn1_g  = (const float*)d_in[10];
    const float* bn1_b  = (const float*)d_in[11];
    const float* cW1    = (const float*)d_in[12];
    const float* cb1    = (const float*)d_in[13];
    const float* cbng   = (const float*)d_in[14];
    const float* cbnb   = (const float*)d_in[15];
    const float* cW2    = (const float*)d_in[16];
    const float* cb2    = (const float*)d_in[17];
    const float* bns_g  = (const float*)d_in[18];
    const float* bns_b  = (const float*)d_in[19];
    const float* vW1    = (const float*)d_in[20];
    const float* vb1    = (const float*)d_in[21];
    const float* vbn1_g = (const float*)d_in[22];
    const float* vbn1_b = (const float*)d_in[23];
    const float* vW2    = (const float*)d_in[24];
    const float* vb2    = (const float*)d_in[25];
    const float* vbn2_g = (const float*)d_in[26];
    const float* vbn2_b = (const float*)d_in[27];
    float* outp = (float*)d_out;
    (void)in_sizes; (void)n_in; (void)out_size; (void)ws_size;

    char* w = (char*)d_ws;
    size_t off = 0;
    auto carve = [&](size_t bytes) -> void* {
        void* p = w + off; off = align256(off + bytes); return p;
    };
    // zero-init region
    int*   cursor  = (int*)carve((size_t)NN * 4);
    float* pooled  = (float*)carve((size_t)NG * DH * 4);
    float* pooled2 = (float*)carve((size_t)NG * DH * 4);
    float* stats   = (float*)carve(3072 * 4);
    size_t zbytes = off;
    float *sA[3], *qA[3], *sB[3], *qB[3];
    float* sp = stats;
    for (int i = 0; i < 3; i++) { sA[i] = sp; sp += 256; qA[i] = sp; sp += 256; }
    for (int i = 0; i < 3; i++) { sB[i] = sp; sp += 128; qB[i] = sp; sp += 128; }
    float* sV1 = sp; sp += 256; float* qV1 = sp; sp += 256;
    float* sV2 = sp; sp += 128; float* qV2 = sp; sp += 128;
    // non-zeroed region
    int*   gcnt    = (int*)carve((size_t)NG * 4);
    int*   rowptr  = (int*)carve((size_t)(NN + 1) * 4);
    int*   slot    = (int*)carve((size_t)NE * 4);
    int*   esrc    = (int*)carve((size_t)NE * 4);
    int*   part    = (int*)carve((size_t)SCB * 4);
    _Float16* vfeat = (_Float16*)carve((size_t)NG * DH * 2);
    _Float16* zin   = (_Float16*)carve((size_t)NG * DH * 2);
    _Float16* zb    = (_Float16*)carve((size_t)NG * DH2 * 2);
    _Float16* vraw  = (_Float16*)carve((size_t)NG * DH * 2);
    _Float16* xh    = (_Float16*)carve((size_t)NN * DH * 2);
    _Float16* hb    = (_Float16*)carve((size_t)NN * DH * 2);
    _Float16* b1    = (_Float16*)carve((size_t)NN * DH2 * 2);
    _Float16* abuf  = (_Float16*)carve((size_t)NN * DH * 2);
    _Float16* Wt[8];
    // shapes: [0]=c1_W1 128x256, [1]=c1_W2 256x128, [2]=cW1_0, [3]=cW2_0,
    //         [4]=cW1_1, [5]=cW2_1, [6]=vW1, [7]=vW2
    for (int i = 0; i < 8; i++) Wt[i] = (_Float16*)carve((size_t)DH * DH2 * 2);

    WPack wp;
    wp.w[0] = c1_W1;            wp.K[0] = 128; wp.N[0] = 256;
    wp.w[1] = c1_W2;            wp.K[1] = 256; wp.N[1] = 128;
    wp.w[2] = cW1;              wp.K[2] = 128; wp.N[2] = 256;
    wp.w[3] = cW2;              wp.K[3] = 256; wp.N[3] = 128;
    wp.w[4] = cW1 + 128 * 256;  wp.K[4] = 128; wp.N[4] = 256;
    wp.w[5] = cW2 + 256 * 128;  wp.K[5] = 256; wp.N[5] = 128;
    wp.w[6] = vW1;              wp.K[6] = 128; wp.N[6] = 256;
    wp.w[7] = vW2;              wp.K[7] = 256; wp.N[7] = 128;
    for (int i = 0; i < 8; i++) wp.wt[i] = Wt[i];

    const int GB = (NN + 127) / 128;  // 782
    dim3 gemmA(GB, 2), gemmB(GB, 1);  // NC=256 / NC=128
    const float* NUL = nullptr;

    hipMemsetAsync(d_ws, 0, zbytes, stream);
    countslot_k<<<782, 256, 0, stream>>>(ei, cursor, slot);
    scan1_k<<<SCB, 256, 0, stream>>>(cursor, part);
    scan2_k<<<1, 64, 0, stream>>>(part, rowptr);
    scan3_k<<<SCB, 256, 0, stream>>>(cursor, part, rowptr);
    place_k<<<782, 256, 0, stream>>>(ei, rowptr, slot, esrc);
    gbound_k<<<2, 256, 0, stream>>>(batch, gcnt);
    wtrans_k<<<dim3(8, 8, 8), 256, 0, stream>>>(wp);
    vinit_k<<<(NG * DH + 255) / 256, 256, 0, stream>>>(vn_emb, vfeat);
    castx_k<<<(NN * 16 + 255) / 256, 256, 0, stream>>>(x, xh);

    // ---- layer 1 ----
    agg_k<<<NN / 4, 256, 0, stream>>>(xh, rowptr, esrc, hb);
    mgemm_k<128, 256><<<gemmA, 256, 0, stream>>>(hb, Wt[0], c1_b1, b1, sA[0], qA[0], NN,
                                                 NUL, NUL, NUL, NUL);
    mgemm_k<256, 128><<<gemmB, 256, 0, stream>>>(b1, Wt[1], c1_b2, abuf, sB[0], qB[0], NN,
                                                 sA[0], qA[0], c1_bng, c1_bnb);
    // bn1 + relu + fused vn-add (layer2 input = relu(bn(...)) + vfeat0[batch])
    bnrelu_k<<<2048, 256, 0, stream>>>(abuf, abuf, sB[0], qB[0], bn1_g, bn1_b,
                                       vfeat, batch, NN);

    // ---- layer 2 ----
    agg_k<<<NN / 4, 256, 0, stream>>>(abuf, rowptr, esrc, hb);
    mgemm_k<128, 256><<<gemmA, 256, 0, stream>>>(hb, Wt[2], cb1, b1, sA[1], qA[1], NN,
                                                 NUL, NUL, NUL, NUL);
    mgemm_k<256, 128><<<gemmB, 256, 0, stream>>>(b1, Wt[3], cb2, abuf, sB[1], qB[1], NN,
                                                 sA[1], qA[1], cbng, cbnb);
    bnpool_k<<<GB, 256, 0, stream>>>(abuf, abuf, sB[1], qB[1], bns_g, bns_b,
                                     batch, pooled, NN, 1);

    // ---- virtual-node MLP (M = 512) ----
    zin_k<<<(NG * DH + 255) / 256, 256, 0, stream>>>(pooled, vfeat, zin);
    mgemm_k<128, 256><<<dim3(4, 2), 256, 0, stream>>>(zin, Wt[6], vb1, zb, sV1, qV1, NG,
                                                      NUL, NUL, NUL, NUL);
    mgemm_k<256, 128><<<dim3(4, 1), 256, 0, stream>>>(zb, Wt[7], vb2, vraw, sV2, qV2, NG,
                                                      sV1, qV1, vbn1_g, vbn1_b);
    bnrelu_k<<<32, 256, 0, stream>>>(vraw, vfeat, sV2, qV2, vbn2_g, vbn2_b,
                                     nullptr, nullptr, NG);

    // ---- layer 3 ----
    addvn_k<<<(NN * 16 + 255) / 256, 256, 0, stream>>>(abuf, vfeat, batch);
    agg_k<<<NN / 4, 256, 0, stream>>>(abuf, rowptr, esrc, hb);
    mgemm_k<128, 256><<<gemmA, 256, 0, stream>>>(hb, Wt[4], cb1 + 256, b1, sA[2], qA[2], NN,
                                                 NUL, NUL, NUL, NUL);
    mgemm_k<256, 128><<<gemmB, 256, 0, stream>>>(b1, Wt[5], cb2 + 128, abuf, sB[2], qB[2], NN,
                                                 sA[2], qA[2], cbng + 256, cbnb + 256);
    bnpool_k<<<GB, 256, 0, stream>>>(abuf, nullptr, sB[2], qB[2], bns_g + 128, bns_b + 128,
                                     batch, pooled2, NN, 0);

    finalout_k<<<(NG * DH + 255) / 256, 256, 0, stream>>>(pooled2, gcnt, outp);
}